// Round 6
// baseline (794.935 us; speedup 1.0000x reference)
//
#include <hip/hip_runtime.h>

// ---------------- problem constants ----------------
#define T_TOK 8192      // B*S tokens
#define D_DIM 1024
#define F_DIM 4096
#define E_EXP 8
#define DT_DIM 256
#define GBLK 256        // gating blocks (32 tokens each)

// ---------------- workspace layout (bytes) ----------------
#define A_XB   0u                    // bf16 X   [8192][1024]   16,777,216
#define A_WT   16777216u             // bf16 W1T then W2T       67,108,864
#define A_H    83886080u             // bf16 h   [17408][4096] 142,606,336
#define A_Y    226492416u            // bf16 Y   [17408][1024]  35,651,584
#define A_META 262144000u
// meta byte offsets
#define MO_FILL   0        // 8 ints (atomic fill cursors)
#define MO_PB     64       // 9 ints (expert segment bases)
#define MO_NT     128      // 1 int
#define MO_PARTP  256      // f32[256][8] per-block prob partials (8KB)
#define MO_PARTC  8448     // int[256][8] per-block count partials (8KB)
#define MO_TILEE  16640    // int[160]
#define MO_TILERB 17664    // int[160]
#define MO_ROUTEE 18688    // int[16384]
#define MO_ROUTEW 84224    // f32[16384]
#define MO_TSLOT  149760   // int[16384]
#define MO_PTOK   215296   // int[17408]
#define META_BYTES 284928
#define META_INTS  (META_BYTES/4)

using bf16x8 = __attribute__((ext_vector_type(8))) short;
using f32x4  = __attribute__((ext_vector_type(4))) float;
typedef unsigned short u16;

__device__ __forceinline__ u16 f2bf(float f) {
  union { float f; unsigned u; } v; v.f = f;
  unsigned r = v.u + 0x7FFFu + ((v.u >> 16) & 1u);   // RNE
  return (u16)(r >> 16);
}
__device__ __forceinline__ float bf2f(u16 h) {
  union { unsigned u; float f; } v; v.u = ((unsigned)h) << 16; return v.f;
}
__device__ __forceinline__ void gload16(const void* gsrc, void* ldst) {
  __builtin_amdgcn_global_load_lds(
      (const __attribute__((address_space(1))) void*)gsrc,
      (__attribute__((address_space(3))) void*)ldst, 16, 0, 0);
}

// ---------------- zero meta ----------------
__global__ void zerok(int* p, int n) {
  int i = blockIdx.x * 256 + threadIdx.x;
  if (i < n) p[i] = 0;
}

// ---------------- transpose + f32->bf16 convert ----------------
__global__ __launch_bounds__(256) void tcvt(const float* __restrict__ src,
                                            u16* __restrict__ dst, int R, int C) {
  __shared__ u16 tile[32][33];
  size_t off = (size_t)blockIdx.z * R * C;
  int cb = blockIdx.x * 32, rb = blockIdx.y * 32;
  int tx = threadIdx.x & 31, ty = threadIdx.x >> 5;
#pragma unroll
  for (int i = 0; i < 4; i++)
    tile[ty + i * 8][tx] = f2bf(src[off + (size_t)(rb + ty + i * 8) * C + cb + tx]);
  __syncthreads();
#pragma unroll
  for (int i = 0; i < 4; i++)
    dst[off + (size_t)(cb + ty + i * 8) * R + rb + tx] = tile[tx][ty + i * 8];
}

// ---------------- gating (+ X -> bf16), NO atomics ----------------
__global__ __launch_bounds__(256) void gating(
    const float* __restrict__ X, const float* __restrict__ TP,
    const float* __restrict__ Wg, const float* __restrict__ bg,
    const float* __restrict__ Wt, const float* __restrict__ bgt,
    const float* __restrict__ alphaP, u16* __restrict__ Xb, int* meta) {
  __shared__ float WgT[E_EXP * D_DIM];   // [e][d] 32KB
  __shared__ float WtT[E_EXP * DT_DIM];  // 8KB
  __shared__ float wsP[4][8];
  __shared__ int   wsC[4][8];
  int tid = threadIdx.x;
  for (int i = tid; i < E_EXP * D_DIM; i += 256) { int d = i >> 3, e = i & 7; WgT[e * D_DIM + d] = Wg[i]; }
  for (int i = tid; i < E_EXP * DT_DIM; i += 256) { int d = i >> 3, e = i & 7; WtT[e * DT_DIM + d] = Wt[i]; }
  __syncthreads();
  int lane = tid & 63, wid = tid >> 6;
  int tb = blockIdx.x * 32;
  int b = tb >> 11;  // S=2048
  float alpha = alphaP[0];

  float tac[8] = {};
#pragma unroll
  for (int i = 0; i < 4; i++) {
    int d = lane + i * 64;
    float x = TP[b * DT_DIM + d];
#pragma unroll
    for (int e = 0; e < 8; e++) tac[e] += x * WtT[e * DT_DIM + d];
  }
  for (int off = 32; off > 0; off >>= 1)
#pragma unroll
    for (int e = 0; e < 8; e++) tac[e] += __shfl_xor(tac[e], off);
  float tl[8];
#pragma unroll
  for (int e = 0; e < 8; e++) tl[e] = alpha * (tac[e] + bgt[e]);

  float psum[8] = {};
  int   cnt[8] = {};
  for (int i = 0; i < 8; i++) {
    int t = tb + wid * 8 + i;
    const float* xr = X + (size_t)t * D_DIM;
    float acc[8] = {};
    u16 xb[16];
#pragma unroll 4
    for (int j = 0; j < 16; j++) {
      int d = lane + j * 64;
      float x = xr[d];
      xb[j] = f2bf(x);
#pragma unroll
      for (int e = 0; e < 8; e++) acc[e] += x * WgT[e * D_DIM + d];
    }
#pragma unroll
    for (int j = 0; j < 16; j++) Xb[(size_t)t * D_DIM + lane + j * 64] = xb[j];
    for (int off = 32; off > 0; off >>= 1)
#pragma unroll
      for (int e = 0; e < 8; e++) acc[e] += __shfl_xor(acc[e], off);
    float gl[8];
#pragma unroll
    for (int e = 0; e < 8; e++) gl[e] = (1.f - alpha) * (acc[e] + bg[e]) + tl[e];
    int e1 = 0;
#pragma unroll
    for (int e = 1; e < 8; e++) if (gl[e] > gl[e1]) e1 = e;
    int es = (e1 == 0) ? 1 : 0;
#pragma unroll
    for (int e = 0; e < 8; e++) if (e != e1 && gl[e] > gl[es]) es = e;
    float mx = gl[0];
#pragma unroll
    for (int e = 1; e < 8; e++) mx = fmaxf(mx, gl[e]);
    float pe[8], se = 0.f;
#pragma unroll
    for (int e = 0; e < 8; e++) { pe[e] = __expf(gl[e] - mx); se += pe[e]; }
    float inv = 1.f / se;
    if (lane == 0) {
#pragma unroll
      for (int e = 0; e < 8; e++) psum[e] += pe[e] * inv;
      cnt[e1]++; cnt[es]++;
      float w1 = 1.f / (1.f + __expf(gl[es] - gl[e1]));
      meta[MO_ROUTEE / 4 + 2 * t] = e1;
      meta[MO_ROUTEE / 4 + 2 * t + 1] = es;
      ((float*)meta)[MO_ROUTEW / 4 + 2 * t] = w1;
      ((float*)meta)[MO_ROUTEW / 4 + 2 * t + 1] = 1.f - w1;
    }
  }
  if (lane == 0) {
#pragma unroll
    for (int e = 0; e < 8; e++) { wsP[wid][e] = psum[e]; wsC[wid][e] = cnt[e]; }
  }
  __syncthreads();
  if (tid < 8) {
    float p = wsP[0][tid] + wsP[1][tid] + wsP[2][tid] + wsP[3][tid];
    int   c = wsC[0][tid] + wsC[1][tid] + wsC[2][tid] + wsC[3][tid];
    ((float*)meta)[MO_PARTP / 4 + blockIdx.x * 8 + tid] = p;
    meta[MO_PARTC / 4 + blockIdx.x * 8 + tid] = c;
  }
}

// ---------------- plan: 256-row tiles (segments stay 128-aligned) ----------------
__global__ void plan(int* meta, float* out) {
  __shared__ float sp[8];
  __shared__ int   sc[8];
  int tid = threadIdx.x;
  if (blockIdx.x != 0) return;
  if (tid < 8) {
    const float* pp = (const float*)meta + MO_PARTP / 4;
    const int*   pc = meta + MO_PARTC / 4;
    float p = 0.f; int c = 0;
    for (int b = 0; b < GBLK; b++) { p += pp[b * 8 + tid]; c += pc[b * 8 + tid]; }
    sp[tid] = p; sc[tid] = c;
  }
  __syncthreads();
  if (tid == 0) {
    int* pb = meta + MO_PB / 4;
    int* tileE = meta + MO_TILEE / 4;
    int* tileRB = meta + MO_TILERB / 4;
    int base = 0, nt = 0;
    float la = 0.f;
    for (int e = 0; e < 8; e++) {
      int n = sc[e];
      pb[e] = base;
      int seg = ((n + 127) >> 7) << 7;          // 128-aligned segment length
      int ntl = (seg + 255) >> 8;               // 256-row tiles
      for (int i = 0; i < ntl; i++) { tileE[nt] = e; tileRB[nt] = base + (i << 8); nt++; }
      base += seg;
      la += (sp[e] * (1.f / 8192.f)) * ((float)n * (1.f / 8192.f));
    }
    pb[8] = base;
    meta[MO_NT / 4] = nt;
    out[T_TOK * D_DIM] = la;  // l_aux
  }
}

// ---------------- fill slot lists (wave-aggregated atomics) ----------------
__global__ __launch_bounds__(256) void fillk(int* meta) {
  int t = blockIdx.x * 256 + threadIdx.x;
  int lane = threadIdx.x & 63;
  int* pb = meta + MO_PB / 4;
  int* fl = meta + MO_FILL / 4;
  int* ptok = meta + MO_PTOK / 4;
  int* ts = meta + MO_TSLOT / 4;
  unsigned long long lmask = (1ull << lane) - 1;  // lanes below
#pragma unroll
  for (int k = 0; k < 2; k++) {
    int e = meta[MO_ROUTEE / 4 + 2 * t + k];
    int slot = 0;
    for (int ee = 0; ee < 8; ee++) {
      unsigned long long mask = __ballot(e == ee);
      if (e == ee) {
        int low = __ffsll((long long)mask) - 1;
        int pre = __popcll(mask & lmask);
        int base = 0;
        if (lane == low) base = atomicAdd(&fl[ee], __popcll(mask));
        base = __shfl(base, low);
        slot = pb[ee] + base + pre;
      }
    }
    ptok[slot] = t;
    ts[2 * t + k] = slot;
  }
}

// =====================================================================
// 256x256 grouped GEMM, BK=64, 512 thr / 8 waves (2Mx4N), per-wave
// 128x64 output (acc[8][4]). 8-phase-style schedule (m201 skeleton):
// tile top: STAGE_ALL(kt+1) then counted vmcnt(8) (waits only tile kt's
// loads; kt+1's stay in flight) + s_barrier. Then 4 phases, each:
//   {4 ds_read (m-pair x 2kk), s_barrier, lgkmcnt(0)+sched_barrier,
//    setprio(1), 16 MFMA (kk->m->n, acc reuse distance 8), setprio(0),
//    s_barrier}.  B frags (8 reads) loaded once in phase 0, held in regs.
// Race proof: passing a phase's closing barrier implies all waves passed
// lgkmcnt(0) -> all reads of buf c done before next tile's STAGE hits it.
// T2 XOR swizzle: linear LDS dest, pre-swizzled global src, swizzled read.
// =====================================================================

#define GEMM_PRE                                                              \
  __shared__ short sA[2][256 * 64];                                           \
  __shared__ short sB[2][256 * 64];                                           \
  int tid = threadIdx.x, lane = tid & 63, wid = tid >> 6;                     \
  int wr = wid >> 2, wc = wid & 3;                                            \
  int sw8 = ((tid & 7) ^ ((tid >> 3) & 7)) * 8;                               \
  int dstb = tid * 16;                                                        \
  f32x4 acc[8][4] = {};                                                       \
  int rA = wr * 128 + (lane & 15);                                            \
  int rB = wc * 64 + (lane & 15);                                             \
  int gx = lane & 7, gb = lane >> 4;

#define GEMM_STAGE(buf, kt)                                                   \
  _Pragma("unroll") for (int l = 0; l < 4; l++) {                             \
    gload16(srcA[l] + (size_t)(kt) * 64, (char*)&sA[buf][0] + l * 8192 + dstb); \
    gload16(srcB[l] + (size_t)(kt) * 64, (char*)&sB[buf][0] + l * 8192 + dstb); \
  }

#define GEMM_PHASE(p, EXTRA)                                                  \
  {                                                                           \
    bf16x8 aR[2][2];                                                          \
    _Pragma("unroll") for (int mi = 0; mi < 2; mi++)                          \
      _Pragma("unroll") for (int kk = 0; kk < 2; kk++)                        \
        aR[mi][kk] = *(const bf16x8*)(pA + (rA + ((p) * 2 + mi) * 16) * 64 + (((kk * 4 + gb) ^ gx) * 8)); \
    EXTRA                                                                     \
    asm volatile("s_barrier" ::: "memory");                                   \
    asm volatile("s_waitcnt lgkmcnt(0)" ::: "memory");                        \
    __builtin_amdgcn_sched_barrier(0);                                        \
    __builtin_amdgcn_s_setprio(1);                                            \
    _Pragma("unroll") for (int kk = 0; kk < 2; kk++)                          \
      _Pragma("unroll") for (int mi = 0; mi < 2; mi++)                        \
        _Pragma("unroll") for (int n = 0; n < 4; n++)                         \
          acc[(p) * 2 + mi][n] = __builtin_amdgcn_mfma_f32_16x16x32_bf16(     \
              aR[mi][kk], bR[n][kk], acc[(p) * 2 + mi][n], 0, 0, 0);          \
    __builtin_amdgcn_s_setprio(0);                                            \
    asm volatile("s_barrier" ::: "memory");                                   \
  }

#define B_READS                                                               \
  _Pragma("unroll") for (int n = 0; n < 4; n++)                               \
    _Pragma("unroll") for (int kk = 0; kk < 2; kk++)                          \
      bR[n][kk] = *(const bf16x8*)(pB + (rB + n * 16) * 64 + (((kk * 4 + gb) ^ gx) * 8));

#define GEMM_LOOP(NK)                                                         \
  GEMM_STAGE(0, 0)                                                            \
  for (int kt = 0; kt < (NK); kt++) {                                         \
    int c = kt & 1;                                                           \
    if (kt + 1 < (NK)) {                                                      \
      GEMM_STAGE(c ^ 1, kt + 1)                                               \
      asm volatile("s_waitcnt vmcnt(8)" ::: "memory");                        \
    } else {                                                                  \
      asm volatile("s_waitcnt vmcnt(0)" ::: "memory");                        \
    }                                                                         \
    asm volatile("s_barrier" ::: "memory");                                   \
    const short* pA = &sA[c][0];                                              \
    const short* pB = &sB[c][0];                                              \
    bf16x8 bR[4][2];                                                          \
    GEMM_PHASE(0, B_READS)                                                    \
    GEMM_PHASE(1, )                                                           \
    GEMM_PHASE(2, )                                                           \
    GEMM_PHASE(3, )                                                           \
  }

// ---------------- GEMM1: h = silu(X[tok] @ W1[e] + b1[e]) ----------------
// grid 1152 = 72 rowtile x 16 colblk, XCD-chunked (144/XCD).
__global__ __launch_bounds__(512, 2) void gemm1(
    const u16* __restrict__ Xb, const u16* __restrict__ W1T,
    const float* __restrict__ b1, u16* __restrict__ H, const int* __restrict__ meta) {
  int id = blockIdx.x;
  int wg = (id & 7) * 144 + (id >> 3);
  int bt = wg >> 4, cbi = wg & 15;
  int nt = meta[MO_NT / 4];
  if (bt >= nt) return;
  int e = meta[MO_TILEE / 4 + bt];
  int rb = meta[MO_TILERB / 4 + bt];
  int rowEnd = meta[MO_PB / 4 + e + 1];
  int cb = cbi * 256;
  const int* ptok = meta + MO_PTOK / 4;

  GEMM_PRE
  const u16* srcA[4];
  const u16* srcB[4];
#pragma unroll
  for (int l = 0; l < 4; l++) {
    int r = l * 64 + (tid >> 3);
    int ri = rb + r; ri = ri < 17407 ? ri : 17407;
    int tok = ptok[ri];
    srcA[l] = Xb + (size_t)tok * D_DIM + sw8;
    srcB[l] = W1T + ((size_t)e * F_DIM + cb + r) * D_DIM + sw8;
  }

  GEMM_LOOP(16)

  int rbase = rb + wr * 128 + ((lane >> 4) << 2);
  int cbase = cb + wc * 64 + (lane & 15);
#pragma unroll
  for (int m = 0; m < 8; m++)
#pragma unroll
    for (int n = 0; n < 4; n++) {
      int f = cbase + n * 16;
      float bias = b1[e * F_DIM + f];
#pragma unroll
      for (int r = 0; r < 4; r++) {
        int p = rbase + m * 16 + r;
        if (p < rowEnd) {
          float v = acc[m][n][r] + bias;
          float s = v * (1.0f / (1.0f + __expf(-v)));
          H[(size_t)p * F_DIM + f] = f2bf(s);
        }
      }
    }
}

// ---------------- GEMM2: Y = h @ W2[e] + b2[e] ----------------
// grid 288 = 72 rowtile x 4 colblk, XCD-chunked (36/XCD).
__global__ __launch_bounds__(512, 2) void gemm2(
    const u16* __restrict__ H, const u16* __restrict__ W2T,
    const float* __restrict__ b2, u16* __restrict__ Y, const int* __restrict__ meta) {
  int id = blockIdx.x;
  int wg = (id & 7) * 36 + (id >> 3);
  int bt = wg >> 2, cbi = wg & 3;
  int nt = meta[MO_NT / 4];
  if (bt >= nt) return;
  int e = meta[MO_TILEE / 4 + bt];
  int rb = meta[MO_TILERB / 4 + bt];
  int rowEnd = meta[MO_PB / 4 + e + 1];
  int cb = cbi * 256;

  GEMM_PRE
  const u16* srcA[4];
  const u16* srcB[4];
#pragma unroll
  for (int l = 0; l < 4; l++) {
    int r = l * 64 + (tid >> 3);
    srcA[l] = H + (size_t)(rb + r) * F_DIM + sw8;
    srcB[l] = W2T + ((size_t)e * D_DIM + cb + r) * F_DIM + sw8;
  }

  GEMM_LOOP(64)

  int rbase = rb + wr * 128 + ((lane >> 4) << 2);
  int cbase = cb + wc * 64 + (lane & 15);
#pragma unroll
  for (int m = 0; m < 8; m++)
#pragma unroll
    for (int n = 0; n < 4; n++) {
      int d = cbase + n * 16;
      float bias = b2[e * D_DIM + d];
#pragma unroll
      for (int r = 0; r < 4; r++) {
        int p = rbase + m * 16 + r;
        if (p < rowEnd)
          Y[(size_t)p * D_DIM + d] = f2bf(acc[m][n][r] + bias);
      }
    }
}

// ---------------- combine: out[t] = w1*Y[s1] + w2*Y[s2] ----------------
__global__ __launch_bounds__(256) void combine(const u16* __restrict__ Y,
                                               const int* __restrict__ meta,
                                               float* __restrict__ out) {
  int t = blockIdx.x;
  const int* ts = meta + MO_TSLOT / 4;
  const float* rw = (const float*)meta + MO_ROUTEW / 4;
  int s1 = ts[2 * t], s2 = ts[2 * t + 1];
  float w1 = rw[2 * t], w2 = rw[2 * t + 1];
  int d0 = threadIdx.x * 4;
  ushort4 a = *(const ushort4*)(Y + (size_t)s1 * D_DIM + d0);
  ushort4 b = *(const ushort4*)(Y + (size_t)s2 * D_DIM + d0);
  float4 v;
  v.x = w1 * bf2f(a.x) + w2 * bf2f(b.x);
  v.y = w1 * bf2f(a.y) + w2 * bf2f(b.y);
  v.z = w1 * bf2f(a.z) + w2 * bf2f(b.z);
  v.w = w1 * bf2f(a.w) + w2 * bf2f(b.w);
  *(float4*)(out + (size_t)t * D_DIM + d0) = v;
}

// ---------------- launch ----------------
extern "C" void kernel_launch(void* const* d_in, const int* in_sizes, int n_in,
                              void* d_out, int out_size, void* d_ws, size_t ws_size,
                              hipStream_t stream) {
  (void)in_sizes; (void)n_in; (void)out_size; (void)ws_size;
  const float* X    = (const float*)d_in[0];
  const float* TP   = (const float*)d_in[1];
  const float* Wg   = (const float*)d_in[2];
  const float* bg   = (const float*)d_in[3];
  const float* Wt   = (const float*)d_in[4];
  const float* bgt  = (const float*)d_in[5];
  const float* alp  = (const float*)d_in[6];
  const float* W1   = (const float*)d_in[7];
  const float* b1   = (const float*)d_in[8];
  const float* W2   = (const float*)d_in[9];
  const float* b2   = (const float*)d_in[10];
  float* out = (float*)d_out;
  char* ws = (char*)d_ws;
  u16* Xb = (u16*)(ws + A_XB);
  u16* WT = (u16*)(ws + A_WT);
  u16* H  = (u16*)(ws + A_H);
  u16* Y  = (u16*)(ws + A_Y);
  int* meta = (int*)(ws + A_META);

  zerok<<<(META_INTS + 255) / 256, 256, 0, stream>>>(meta, META_INTS);
  tcvt<<<dim3(F_DIM / 32, D_DIM / 32, E_EXP), 256, 0, stream>>>(W1, WT, D_DIM, F_DIM); // W1T [F][D]
  gating<<<GBLK, 256, 0, stream>>>(X, TP, Wg, bg, Wt, bgt, alp, Xb, meta);
  plan<<<1, 64, 0, stream>>>(meta, out);
  fillk<<<T_TOK / 256, 256, 0, stream>>>(meta);
  gemm1<<<1152, 512, 0, stream>>>(Xb, WT, b1, H, meta);
  tcvt<<<dim3(D_DIM / 32, F_DIM / 32, E_EXP), 256, 0, stream>>>(W2, WT, F_DIM, D_DIM); // W2T [D][F]
  gemm2<<<288, 512, 0, stream>>>(H, WT, b2, Y, meta);
  combine<<<T_TOK, 256, 0, stream>>>(Y, meta, out);
}

// Round 7
// 618.683 us; speedup vs baseline: 1.2849x; 1.2849x over previous
//
#include <hip/hip_runtime.h>

// ---------------- problem constants ----------------
#define T_TOK 8192      // B*S tokens
#define D_DIM 1024
#define F_DIM 4096
#define E_EXP 8
#define DT_DIM 256
#define GBLK 256        // gating blocks (32 tokens each)

// ---------------- workspace layout (bytes) ----------------
#define A_XB   0u                    // bf16 X   [8192][1024]   16,777,216
#define A_WT   16777216u             // bf16 W1T then W2T       67,108,864
#define A_H    83886080u             // bf16 h   [17408][4096] 142,606,336
#define A_Y    226492416u            // bf16 Y   [17408][1024]  35,651,584
#define A_META 262144000u
// meta byte offsets
#define MO_FILL   0        // 8 ints (atomic fill cursors)
#define MO_PB     64       // 9 ints (expert segment bases)
#define MO_NT     128      // 1 int
#define MO_PARTP  256      // f32[256][8] per-block prob partials (8KB)
#define MO_PARTC  8448     // int[256][8] per-block count partials (8KB)
#define MO_TILEE  16640    // int[160]
#define MO_TILERB 17664    // int[160]
#define MO_ROUTEE 18688    // int[16384]
#define MO_ROUTEW 84224    // f32[16384]
#define MO_TSLOT  149760   // int[16384]
#define MO_PTOK   215296   // int[17408]
#define META_BYTES 284928
#define META_INTS  (META_BYTES/4)

using bf16x8 = __attribute__((ext_vector_type(8))) short;
using f32x4  = __attribute__((ext_vector_type(4))) float;
typedef unsigned short u16;

__device__ __forceinline__ u16 f2bf(float f) {
  union { float f; unsigned u; } v; v.f = f;
  unsigned r = v.u + 0x7FFFu + ((v.u >> 16) & 1u);   // RNE
  return (u16)(r >> 16);
}
__device__ __forceinline__ float bf2f(u16 h) {
  union { unsigned u; float f; } v; v.u = ((unsigned)h) << 16; return v.f;
}
__device__ __forceinline__ void gload16(const void* gsrc, void* ldst) {
  __builtin_amdgcn_global_load_lds(
      (const __attribute__((address_space(1))) void*)gsrc,
      (__attribute__((address_space(3))) void*)ldst, 16, 0, 0);
}

// ---------------- zero meta ----------------
__global__ void zerok(int* p, int n) {
  int i = blockIdx.x * 256 + threadIdx.x;
  if (i < n) p[i] = 0;
}

// ---------------- transpose + f32->bf16 convert ----------------
__global__ __launch_bounds__(256) void tcvt(const float* __restrict__ src,
                                            u16* __restrict__ dst, int R, int C) {
  __shared__ u16 tile[32][33];
  size_t off = (size_t)blockIdx.z * R * C;
  int cb = blockIdx.x * 32, rb = blockIdx.y * 32;
  int tx = threadIdx.x & 31, ty = threadIdx.x >> 5;
#pragma unroll
  for (int i = 0; i < 4; i++)
    tile[ty + i * 8][tx] = f2bf(src[off + (size_t)(rb + ty + i * 8) * C + cb + tx]);
  __syncthreads();
#pragma unroll
  for (int i = 0; i < 4; i++)
    dst[off + (size_t)(cb + ty + i * 8) * R + rb + tx] = tile[tx][ty + i * 8];
}

// ---------------- gating (+ X -> bf16), NO atomics ----------------
__global__ __launch_bounds__(256) void gating(
    const float* __restrict__ X, const float* __restrict__ TP,
    const float* __restrict__ Wg, const float* __restrict__ bg,
    const float* __restrict__ Wt, const float* __restrict__ bgt,
    const float* __restrict__ alphaP, u16* __restrict__ Xb, int* meta) {
  __shared__ float WgT[E_EXP * D_DIM];   // [e][d] 32KB
  __shared__ float WtT[E_EXP * DT_DIM];  // 8KB
  __shared__ float wsP[4][8];
  __shared__ int   wsC[4][8];
  int tid = threadIdx.x;
  for (int i = tid; i < E_EXP * D_DIM; i += 256) { int d = i >> 3, e = i & 7; WgT[e * D_DIM + d] = Wg[i]; }
  for (int i = tid; i < E_EXP * DT_DIM; i += 256) { int d = i >> 3, e = i & 7; WtT[e * DT_DIM + d] = Wt[i]; }
  __syncthreads();
  int lane = tid & 63, wid = tid >> 6;
  int tb = blockIdx.x * 32;
  int b = tb >> 11;  // S=2048
  float alpha = alphaP[0];

  float tac[8] = {};
#pragma unroll
  for (int i = 0; i < 4; i++) {
    int d = lane + i * 64;
    float x = TP[b * DT_DIM + d];
#pragma unroll
    for (int e = 0; e < 8; e++) tac[e] += x * WtT[e * DT_DIM + d];
  }
  for (int off = 32; off > 0; off >>= 1)
#pragma unroll
    for (int e = 0; e < 8; e++) tac[e] += __shfl_xor(tac[e], off);
  float tl[8];
#pragma unroll
  for (int e = 0; e < 8; e++) tl[e] = alpha * (tac[e] + bgt[e]);

  float psum[8] = {};
  int   cnt[8] = {};
  for (int i = 0; i < 8; i++) {
    int t = tb + wid * 8 + i;
    const float* xr = X + (size_t)t * D_DIM;
    float acc[8] = {};
    u16 xb[16];
#pragma unroll 4
    for (int j = 0; j < 16; j++) {
      int d = lane + j * 64;
      float x = xr[d];
      xb[j] = f2bf(x);
#pragma unroll
      for (int e = 0; e < 8; e++) acc[e] += x * WgT[e * D_DIM + d];
    }
#pragma unroll
    for (int j = 0; j < 16; j++) Xb[(size_t)t * D_DIM + lane + j * 64] = xb[j];
    for (int off = 32; off > 0; off >>= 1)
#pragma unroll
      for (int e = 0; e < 8; e++) acc[e] += __shfl_xor(acc[e], off);
    float gl[8];
#pragma unroll
    for (int e = 0; e < 8; e++) gl[e] = (1.f - alpha) * (acc[e] + bg[e]) + tl[e];
    int e1 = 0;
#pragma unroll
    for (int e = 1; e < 8; e++) if (gl[e] > gl[e1]) e1 = e;
    int es = (e1 == 0) ? 1 : 0;
#pragma unroll
    for (int e = 0; e < 8; e++) if (e != e1 && gl[e] > gl[es]) es = e;
    float mx = gl[0];
#pragma unroll
    for (int e = 1; e < 8; e++) mx = fmaxf(mx, gl[e]);
    float pe[8], se = 0.f;
#pragma unroll
    for (int e = 0; e < 8; e++) { pe[e] = __expf(gl[e] - mx); se += pe[e]; }
    float inv = 1.f / se;
    if (lane == 0) {
#pragma unroll
      for (int e = 0; e < 8; e++) psum[e] += pe[e] * inv;
      cnt[e1]++; cnt[es]++;
      float w1 = 1.f / (1.f + __expf(gl[es] - gl[e1]));
      meta[MO_ROUTEE / 4 + 2 * t] = e1;
      meta[MO_ROUTEE / 4 + 2 * t + 1] = es;
      ((float*)meta)[MO_ROUTEW / 4 + 2 * t] = w1;
      ((float*)meta)[MO_ROUTEW / 4 + 2 * t + 1] = 1.f - w1;
    }
  }
  if (lane == 0) {
#pragma unroll
    for (int e = 0; e < 8; e++) { wsP[wid][e] = psum[e]; wsC[wid][e] = cnt[e]; }
  }
  __syncthreads();
  if (tid < 8) {
    float p = wsP[0][tid] + wsP[1][tid] + wsP[2][tid] + wsP[3][tid];
    int   c = wsC[0][tid] + wsC[1][tid] + wsC[2][tid] + wsC[3][tid];
    ((float*)meta)[MO_PARTP / 4 + blockIdx.x * 8 + tid] = p;
    meta[MO_PARTC / 4 + blockIdx.x * 8 + tid] = c;
  }
}

// ---------------- plan ----------------
__global__ void plan(int* meta, float* out) {
  __shared__ float sp[8];
  __shared__ int   sc[8];
  int tid = threadIdx.x;
  if (blockIdx.x != 0) return;
  if (tid < 8) {
    const float* pp = (const float*)meta + MO_PARTP / 4;
    const int*   pc = meta + MO_PARTC / 4;
    float p = 0.f; int c = 0;
    for (int b = 0; b < GBLK; b++) { p += pp[b * 8 + tid]; c += pc[b * 8 + tid]; }
    sp[tid] = p; sc[tid] = c;
  }
  __syncthreads();
  if (tid == 0) {
    int* pb = meta + MO_PB / 4;
    int* tileE = meta + MO_TILEE / 4;
    int* tileRB = meta + MO_TILERB / 4;
    int base = 0, nt = 0;
    float la = 0.f;
    for (int e = 0; e < 8; e++) {
      int n = sc[e];
      pb[e] = base;
      int ntl = (n + 127) >> 7;
      for (int i = 0; i < ntl; i++) { tileE[nt] = e; tileRB[nt] = base + (i << 7); nt++; }
      base += ntl << 7;
      la += (sp[e] * (1.f / 8192.f)) * ((float)n * (1.f / 8192.f));
    }
    pb[8] = base;
    meta[MO_NT / 4] = nt;
    out[T_TOK * D_DIM] = la;  // l_aux
  }
}

// ---------------- fill slot lists (wave-aggregated atomics) ----------------
__global__ __launch_bounds__(256) void fillk(int* meta) {
  int t = blockIdx.x * 256 + threadIdx.x;
  int lane = threadIdx.x & 63;
  int* pb = meta + MO_PB / 4;
  int* fl = meta + MO_FILL / 4;
  int* ptok = meta + MO_PTOK / 4;
  int* ts = meta + MO_TSLOT / 4;
  unsigned long long lmask = (1ull << lane) - 1;  // lanes below
#pragma unroll
  for (int k = 0; k < 2; k++) {
    int e = meta[MO_ROUTEE / 4 + 2 * t + k];
    int slot = 0;
    for (int ee = 0; ee < 8; ee++) {
      unsigned long long mask = __ballot(e == ee);
      if (e == ee) {
        int low = __ffsll((long long)mask) - 1;
        int pre = __popcll(mask & lmask);
        int base = 0;
        if (lane == low) base = atomicAdd(&fl[ee], __popcll(mask));
        base = __shfl(base, low);
        slot = pb[ee] + base + pre;
      }
    }
    ptok[slot] = t;
    ts[2 * t + k] = slot;
  }
}

// =====================================================================
// GEMM core (r2 structure): 128x128 tile, BK=32, 16KB LDS, 256 thr,
// 4 waves x 64x64 output, __syncthreads 2-phase — max inter-block TLP
// (~4 blocks/CU hide each other's stalls). NEW vs r2: BK=32 XOR swizzle
// (rule 21: linear LDS dest, source granule ^= (row>>1)&3, read granule
// same XOR) -> 8-way ds_read_b128 conflict becomes 2-way (free).
// =====================================================================

// ---------------- GEMM1: h = silu(X[tok] @ W1[e] + b1[e]) ----------------
// grid (136, 32), block 256. BT layout [F][D].
__global__ __launch_bounds__(256) void gemm1(
    const u16* __restrict__ Xb, const u16* __restrict__ W1T,
    const float* __restrict__ b1, u16* __restrict__ H, const int* __restrict__ meta) {
  int nt = meta[MO_NT / 4];
  int bt = blockIdx.x;
  if (bt >= nt) return;
  int e = meta[MO_TILEE / 4 + bt];
  int rb = meta[MO_TILERB / 4 + bt];
  int cb = blockIdx.y * 128;
  const int* ptok = meta + MO_PTOK / 4;

  __shared__ short sA[128 * 32];
  __shared__ short sB[128 * 32];
  int tid = threadIdx.x, lane = tid & 63, wid = tid >> 6;
  int wr = wid >> 1, wc = wid & 1;
  int r0 = tid >> 2;
  int c0 = (((tid & 3) ^ ((r0 >> 1) & 3)) << 3);   // swizzled source granule
  int tok0 = ptok[rb + r0];
  int tok1 = ptok[rb + r0 + 64];
  const u16* gA0 = Xb + (size_t)tok0 * D_DIM + c0;
  const u16* gA1 = Xb + (size_t)tok1 * D_DIM + c0;
  const u16* gB0 = W1T + ((size_t)e * F_DIM + cb + r0) * D_DIM + c0;
  const u16* gB1 = gB0 + (size_t)64 * D_DIM;
  char* lA = (char*)sA + wid * 1024;
  char* lB = (char*)sB + wid * 1024;

  f32x4 acc[4][4] = {};
  int kb = (((lane >> 4) ^ (((lane & 15) >> 1) & 3)) << 3);  // swizzled read granule
  for (int k0 = 0; k0 < D_DIM; k0 += 32) {
    __syncthreads();
    gload16(gA0 + k0, lA);
    gload16(gA1 + k0, lA + 4096);
    gload16(gB0 + k0, lB);
    gload16(gB1 + k0, lB + 4096);
    __syncthreads();
    bf16x8 af[4], bfr[4];
    int ra = wr * 64 + (lane & 15);
#pragma unroll
    for (int m = 0; m < 4; m++)
      af[m] = *(const bf16x8*)((const char*)sA + ((ra + m * 16) * 32 + kb) * 2);
    int rn = wc * 64 + (lane & 15);
#pragma unroll
    for (int n = 0; n < 4; n++)
      bfr[n] = *(const bf16x8*)((const char*)sB + ((rn + n * 16) * 32 + kb) * 2);
#pragma unroll
    for (int m = 0; m < 4; m++)
#pragma unroll
      for (int n = 0; n < 4; n++)
        acc[m][n] = __builtin_amdgcn_mfma_f32_16x16x32_bf16(af[m], bfr[n], acc[m][n], 0, 0, 0);
  }
  int rbase = wr * 64 + ((lane >> 4) << 2);
  int cbase = cb + wc * 64 + (lane & 15);
#pragma unroll
  for (int m = 0; m < 4; m++)
#pragma unroll
    for (int n = 0; n < 4; n++) {
      int f = cbase + n * 16;
      float bias = b1[e * F_DIM + f];
#pragma unroll
      for (int r = 0; r < 4; r++) {
        int p = rb + rbase + m * 16 + r;
        float v = acc[m][n][r] + bias;
        float s = v * (1.0f / (1.0f + __expf(-v)));
        H[(size_t)p * F_DIM + f] = f2bf(s);
      }
    }
}

// ---------------- GEMM2: Y = h @ W2[e] + b2[e] ----------------
// 1-D grid 1088 = 136 rowtile x 8 colblk, XCD-chunked (136/XCD: 17 row
// tiles x 8 col blocks share H strips in their XCD's L2).
__global__ __launch_bounds__(256) void gemm2(
    const u16* __restrict__ H, const u16* __restrict__ W2T,
    const float* __restrict__ b2, u16* __restrict__ Y, const int* __restrict__ meta) {
  int id = blockIdx.x;
  int wg = (id & 7) * 136 + (id >> 3);   // bijective, 1088 = 8*136
  int bt = wg >> 3;
  int cb = (wg & 7) * 128;
  int nt = meta[MO_NT / 4];
  if (bt >= nt) return;
  int e = meta[MO_TILEE / 4 + bt];
  int rb = meta[MO_TILERB / 4 + bt];
  __shared__ short sA[128 * 32];
  __shared__ short sB[128 * 32];
  int tid = threadIdx.x, lane = tid & 63, wid = tid >> 6;
  int wr = wid >> 1, wc = wid & 1;
  int r0 = tid >> 2;
  int c0 = (((tid & 3) ^ ((r0 >> 1) & 3)) << 3);   // swizzled source granule
  const u16* gA0 = H + (size_t)(rb + r0) * F_DIM + c0;
  const u16* gA1 = gA0 + (size_t)64 * F_DIM;
  const u16* gB0 = W2T + ((size_t)e * D_DIM + cb + r0) * F_DIM + c0;
  const u16* gB1 = gB0 + (size_t)64 * F_DIM;
  char* lA = (char*)sA + wid * 1024;
  char* lB = (char*)sB + wid * 1024;

  f32x4 acc[4][4] = {};
  int kb = (((lane >> 4) ^ (((lane & 15) >> 1) & 3)) << 3);  // swizzled read granule
  for (int k0 = 0; k0 < F_DIM; k0 += 32) {
    __syncthreads();
    gload16(gA0 + k0, lA);
    gload16(gA1 + k0, lA + 4096);
    gload16(gB0 + k0, lB);
    gload16(gB1 + k0, lB + 4096);
    __syncthreads();
    bf16x8 af[4], bfr[4];
    int ra = wr * 64 + (lane & 15);
#pragma unroll
    for (int m = 0; m < 4; m++)
      af[m] = *(const bf16x8*)((const char*)sA + ((ra + m * 16) * 32 + kb) * 2);
    int rn = wc * 64 + (lane & 15);
#pragma unroll
    for (int n = 0; n < 4; n++)
      bfr[n] = *(const bf16x8*)((const char*)sB + ((rn + n * 16) * 32 + kb) * 2);
#pragma unroll
    for (int m = 0; m < 4; m++)
#pragma unroll
      for (int n = 0; n < 4; n++)
        acc[m][n] = __builtin_amdgcn_mfma_f32_16x16x32_bf16(af[m], bfr[n], acc[m][n], 0, 0, 0);
  }
  int rbase = wr * 64 + ((lane >> 4) << 2);
  int cbase = cb + wc * 64 + (lane & 15);
#pragma unroll
  for (int m = 0; m < 4; m++)
#pragma unroll
    for (int n = 0; n < 4; n++) {
      int d = cbase + n * 16;
      float bias = b2[e * D_DIM + d];
#pragma unroll
      for (int r = 0; r < 4; r++) {
        int p = rb + rbase + m * 16 + r;
        Y[(size_t)p * D_DIM + d] = f2bf(acc[m][n][r] + bias);
      }
    }
}

// ---------------- combine: out[t] = w1*Y[s1] + w2*Y[s2] ----------------
__global__ __launch_bounds__(256) void combine(const u16* __restrict__ Y,
                                               const int* __restrict__ meta,
                                               float* __restrict__ out) {
  int t = blockIdx.x;
  const int* ts = meta + MO_TSLOT / 4;
  const float* rw = (const float*)meta + MO_ROUTEW / 4;
  int s1 = ts[2 * t], s2 = ts[2 * t + 1];
  float w1 = rw[2 * t], w2 = rw[2 * t + 1];
  int d0 = threadIdx.x * 4;
  ushort4 a = *(const ushort4*)(Y + (size_t)s1 * D_DIM + d0);
  ushort4 b = *(const ushort4*)(Y + (size_t)s2 * D_DIM + d0);
  float4 v;
  v.x = w1 * bf2f(a.x) + w2 * bf2f(b.x);
  v.y = w1 * bf2f(a.y) + w2 * bf2f(b.y);
  v.z = w1 * bf2f(a.z) + w2 * bf2f(b.z);
  v.w = w1 * bf2f(a.w) + w2 * bf2f(b.w);
  *(float4*)(out + (size_t)t * D_DIM + d0) = v;
}

// ---------------- launch ----------------
extern "C" void kernel_launch(void* const* d_in, const int* in_sizes, int n_in,
                              void* d_out, int out_size, void* d_ws, size_t ws_size,
                              hipStream_t stream) {
  (void)in_sizes; (void)n_in; (void)out_size; (void)ws_size;
  const float* X    = (const float*)d_in[0];
  const float* TP   = (const float*)d_in[1];
  const float* Wg   = (const float*)d_in[2];
  const float* bg   = (const float*)d_in[3];
  const float* Wt   = (const float*)d_in[4];
  const float* bgt  = (const float*)d_in[5];
  const float* alp  = (const float*)d_in[6];
  const float* W1   = (const float*)d_in[7];
  const float* b1   = (const float*)d_in[8];
  const float* W2   = (const float*)d_in[9];
  const float* b2   = (const float*)d_in[10];
  float* out = (float*)d_out;
  char* ws = (char*)d_ws;
  u16* Xb = (u16*)(ws + A_XB);
  u16* WT = (u16*)(ws + A_WT);
  u16* H  = (u16*)(ws + A_H);
  u16* Y  = (u16*)(ws + A_Y);
  int* meta = (int*)(ws + A_META);

  zerok<<<(META_INTS + 255) / 256, 256, 0, stream>>>(meta, META_INTS);
  tcvt<<<dim3(F_DIM / 32, D_DIM / 32, E_EXP), 256, 0, stream>>>(W1, WT, D_DIM, F_DIM); // W1T [F][D]
  gating<<<GBLK, 256, 0, stream>>>(X, TP, Wg, bg, Wt, bgt, alp, Xb, meta);
  plan<<<1, 64, 0, stream>>>(meta, out);
  fillk<<<T_TOK / 256, 256, 0, stream>>>(meta);
  gemm1<<<dim3(136, F_DIM / 128), 256, 0, stream>>>(Xb, WT, b1, H, meta);
  tcvt<<<dim3(D_DIM / 32, F_DIM / 32, E_EXP), 256, 0, stream>>>(W2, WT, F_DIM, D_DIM); // W2T [D][F]
  gemm2<<<1088, 256, 0, stream>>>(H, WT, b2, Y, meta);
  combine<<<T_TOK, 256, 0, stream>>>(Y, meta, out);
}

// Round 8
// 588.173 us; speedup vs baseline: 1.3515x; 1.0519x over previous
//
#include <hip/hip_runtime.h>

// ---------------- problem constants ----------------
#define T_TOK 8192      // B*S tokens
#define D_DIM 1024
#define F_DIM 4096
#define E_EXP 8
#define DT_DIM 256
#define GBLK 256        // gating blocks (32 tokens each)

// ---------------- workspace layout (bytes) ----------------
#define A_XB   0u                    // bf16 X   [8192][1024]   16,777,216
#define A_WT   16777216u             // bf16 W1T then W2T       67,108,864
#define A_H    83886080u             // bf16 h   [17408][4096] 142,606,336
#define A_Y    226492416u            // bf16 Y   [17408][1024]  35,651,584
#define A_META 262144000u
// meta byte offsets
#define MO_FILL   0        // 8 ints (atomic fill cursors)
#define MO_PB     64       // 9 ints (expert segment bases)
#define MO_NT     128      // 1 int
#define MO_PARTP  256      // f32[256][8] per-block prob partials (8KB)
#define MO_PARTC  8448     // int[256][8] per-block count partials (8KB)
#define MO_TILEE  16640    // int[160]
#define MO_TILERB 17664    // int[160]
#define MO_ROUTEE 18688    // int[16384]
#define MO_ROUTEW 84224    // f32[16384]
#define MO_TSLOT  149760   // int[16384]
#define MO_PTOK   215296   // int[17408]
#define META_BYTES 284928
#define META_INTS  (META_BYTES/4)

using bf16x8 = __attribute__((ext_vector_type(8))) short;
using f32x4  = __attribute__((ext_vector_type(4))) float;
typedef unsigned short u16;

__device__ __forceinline__ u16 f2bf(float f) {
  union { float f; unsigned u; } v; v.f = f;
  unsigned r = v.u + 0x7FFFu + ((v.u >> 16) & 1u);   // RNE
  return (u16)(r >> 16);
}
__device__ __forceinline__ float bf2f(u16 h) {
  union { unsigned u; float f; } v; v.u = ((unsigned)h) << 16; return v.f;
}
__device__ __forceinline__ void gload16(const void* gsrc, void* ldst) {
  __builtin_amdgcn_global_load_lds(
      (const __attribute__((address_space(1))) void*)gsrc,
      (__attribute__((address_space(3))) void*)ldst, 16, 0, 0);
}

// ---------------- zero meta ----------------
__global__ void zerok(int* p, int n) {
  int i = blockIdx.x * 256 + threadIdx.x;
  if (i < n) p[i] = 0;
}

// ---------------- transpose + f32->bf16 convert ----------------
__global__ __launch_bounds__(256) void tcvt(const float* __restrict__ src,
                                            u16* __restrict__ dst, int R, int C) {
  __shared__ u16 tile[32][33];
  size_t off = (size_t)blockIdx.z * R * C;
  int cb = blockIdx.x * 32, rb = blockIdx.y * 32;
  int tx = threadIdx.x & 31, ty = threadIdx.x >> 5;
#pragma unroll
  for (int i = 0; i < 4; i++)
    tile[ty + i * 8][tx] = f2bf(src[off + (size_t)(rb + ty + i * 8) * C + cb + tx]);
  __syncthreads();
#pragma unroll
  for (int i = 0; i < 4; i++)
    dst[off + (size_t)(cb + ty + i * 8) * R + rb + tx] = tile[tx][ty + i * 8];
}

// ---------------- gating (+ X -> bf16), NO atomics ----------------
__global__ __launch_bounds__(256) void gating(
    const float* __restrict__ X, const float* __restrict__ TP,
    const float* __restrict__ Wg, const float* __restrict__ bg,
    const float* __restrict__ Wt, const float* __restrict__ bgt,
    const float* __restrict__ alphaP, u16* __restrict__ Xb, int* meta) {
  __shared__ float WgT[E_EXP * D_DIM];   // [e][d] 32KB
  __shared__ float WtT[E_EXP * DT_DIM];  // 8KB
  __shared__ float wsP[4][8];
  __shared__ int   wsC[4][8];
  int tid = threadIdx.x;
  for (int i = tid; i < E_EXP * D_DIM; i += 256) { int d = i >> 3, e = i & 7; WgT[e * D_DIM + d] = Wg[i]; }
  for (int i = tid; i < E_EXP * DT_DIM; i += 256) { int d = i >> 3, e = i & 7; WtT[e * DT_DIM + d] = Wt[i]; }
  __syncthreads();
  int lane = tid & 63, wid = tid >> 6;
  int tb = blockIdx.x * 32;
  int b = tb >> 11;  // S=2048
  float alpha = alphaP[0];

  float tac[8] = {};
#pragma unroll
  for (int i = 0; i < 4; i++) {
    int d = lane + i * 64;
    float x = TP[b * DT_DIM + d];
#pragma unroll
    for (int e = 0; e < 8; e++) tac[e] += x * WtT[e * DT_DIM + d];
  }
  for (int off = 32; off > 0; off >>= 1)
#pragma unroll
    for (int e = 0; e < 8; e++) tac[e] += __shfl_xor(tac[e], off);
  float tl[8];
#pragma unroll
  for (int e = 0; e < 8; e++) tl[e] = alpha * (tac[e] + bgt[e]);

  float psum[8] = {};
  int   cnt[8] = {};
  for (int i = 0; i < 8; i++) {
    int t = tb + wid * 8 + i;
    const float* xr = X + (size_t)t * D_DIM;
    float acc[8] = {};
    u16 xb[16];
#pragma unroll 4
    for (int j = 0; j < 16; j++) {
      int d = lane + j * 64;
      float x = xr[d];
      xb[j] = f2bf(x);
#pragma unroll
      for (int e = 0; e < 8; e++) acc[e] += x * WgT[e * D_DIM + d];
    }
#pragma unroll
    for (int j = 0; j < 16; j++) Xb[(size_t)t * D_DIM + lane + j * 64] = xb[j];
    for (int off = 32; off > 0; off >>= 1)
#pragma unroll
      for (int e = 0; e < 8; e++) acc[e] += __shfl_xor(acc[e], off);
    float gl[8];
#pragma unroll
    for (int e = 0; e < 8; e++) gl[e] = (1.f - alpha) * (acc[e] + bg[e]) + tl[e];
    int e1 = 0;
#pragma unroll
    for (int e = 1; e < 8; e++) if (gl[e] > gl[e1]) e1 = e;
    int es = (e1 == 0) ? 1 : 0;
#pragma unroll
    for (int e = 0; e < 8; e++) if (e != e1 && gl[e] > gl[es]) es = e;
    float mx = gl[0];
#pragma unroll
    for (int e = 1; e < 8; e++) mx = fmaxf(mx, gl[e]);
    float pe[8], se = 0.f;
#pragma unroll
    for (int e = 0; e < 8; e++) { pe[e] = __expf(gl[e] - mx); se += pe[e]; }
    float inv = 1.f / se;
    if (lane == 0) {
#pragma unroll
      for (int e = 0; e < 8; e++) psum[e] += pe[e] * inv;
      cnt[e1]++; cnt[es]++;
      float w1 = 1.f / (1.f + __expf(gl[es] - gl[e1]));
      meta[MO_ROUTEE / 4 + 2 * t] = e1;
      meta[MO_ROUTEE / 4 + 2 * t + 1] = es;
      ((float*)meta)[MO_ROUTEW / 4 + 2 * t] = w1;
      ((float*)meta)[MO_ROUTEW / 4 + 2 * t + 1] = 1.f - w1;
    }
  }
  if (lane == 0) {
#pragma unroll
    for (int e = 0; e < 8; e++) { wsP[wid][e] = psum[e]; wsC[wid][e] = cnt[e]; }
  }
  __syncthreads();
  if (tid < 8) {
    float p = wsP[0][tid] + wsP[1][tid] + wsP[2][tid] + wsP[3][tid];
    int   c = wsC[0][tid] + wsC[1][tid] + wsC[2][tid] + wsC[3][tid];
    ((float*)meta)[MO_PARTP / 4 + blockIdx.x * 8 + tid] = p;
    meta[MO_PARTC / 4 + blockIdx.x * 8 + tid] = c;
  }
}

// ---------------- plan ----------------
__global__ void plan(int* meta, float* out) {
  __shared__ float sp[8];
  __shared__ int   sc[8];
  int tid = threadIdx.x;
  if (blockIdx.x != 0) return;
  if (tid < 8) {
    const float* pp = (const float*)meta + MO_PARTP / 4;
    const int*   pc = meta + MO_PARTC / 4;
    float p = 0.f; int c = 0;
    for (int b = 0; b < GBLK; b++) { p += pp[b * 8 + tid]; c += pc[b * 8 + tid]; }
    sp[tid] = p; sc[tid] = c;
  }
  __syncthreads();
  if (tid == 0) {
    int* pb = meta + MO_PB / 4;
    int* tileE = meta + MO_TILEE / 4;
    int* tileRB = meta + MO_TILERB / 4;
    int base = 0, nt = 0;
    float la = 0.f;
    for (int e = 0; e < 8; e++) {
      int n = sc[e];
      pb[e] = base;
      int ntl = (n + 127) >> 7;
      for (int i = 0; i < ntl; i++) { tileE[nt] = e; tileRB[nt] = base + (i << 7); nt++; }
      base += ntl << 7;
      la += (sp[e] * (1.f / 8192.f)) * ((float)n * (1.f / 8192.f));
    }
    pb[8] = base;
    meta[MO_NT / 4] = nt;
    out[T_TOK * D_DIM] = la;  // l_aux
  }
}

// ---------------- fill slot lists (wave-aggregated atomics) ----------------
__global__ __launch_bounds__(256) void fillk(int* meta) {
  int t = blockIdx.x * 256 + threadIdx.x;
  int lane = threadIdx.x & 63;
  int* pb = meta + MO_PB / 4;
  int* fl = meta + MO_FILL / 4;
  int* ptok = meta + MO_PTOK / 4;
  int* ts = meta + MO_TSLOT / 4;
  unsigned long long lmask = (1ull << lane) - 1;  // lanes below
#pragma unroll
  for (int k = 0; k < 2; k++) {
    int e = meta[MO_ROUTEE / 4 + 2 * t + k];
    int slot = 0;
    for (int ee = 0; ee < 8; ee++) {
      unsigned long long mask = __ballot(e == ee);
      if (e == ee) {
        int low = __ffsll((long long)mask) - 1;
        int pre = __popcll(mask & lmask);
        int base = 0;
        if (lane == low) base = atomicAdd(&fl[ee], __popcll(mask));
        base = __shfl(base, low);
        slot = pb[ee] + base + pre;
      }
    }
    ptok[slot] = t;
    ts[2 * t + k] = slot;
  }
}

// =====================================================================
// GEMM core (r7 + dbuf): 128x128 tile, BK=32, double-buffered 32KB LDS,
// 256 thr, 4 waves x 64x64 output. ONE s_barrier per K-step; stage for
// tile k+1 issued AFTER the barrier; its wait (vmcnt 0) happens at the
// NEXT iteration's top -> load latency covered by a full compute phase
// instead of exposed per-step (r7's syncthreads drained in-step).
// Race proof: lgkmcnt(0)+sched_barrier before barrier_i retires all
// ds_reads of buf c^1 (iter i-1); STAGE(c^1) is after barrier_i.
// vmcnt(0) before barrier_i completes buf c staging before its reads.
// T2 XOR swizzle kept: linear LDS dest, pre-swizzled global source
// granule (^= (row>>1)&3), same XOR on ds_read granule (0 conflicts, r7).
// =====================================================================

// ---------------- GEMM1: h = silu(X[tok] @ W1[e] + b1[e]) ----------------
// 1-D grid 4352 = 8 XCD x 544 (= 136 bt x 4 cb-minor): resident blocks on
// an XCD share A rows across 4 cb and keep B strips ~2MB in its L2.
__global__ __launch_bounds__(256) void gemm1(
    const u16* __restrict__ Xb, const u16* __restrict__ W1T,
    const float* __restrict__ b1, u16* __restrict__ H, const int* __restrict__ meta) {
  int xcd = blockIdx.x & 7, loc = blockIdx.x >> 3;   // 4352 = 8*544
  int bt = loc >> 2;
  int cb = (xcd * 4 + (loc & 3)) * 128;
  int nt = meta[MO_NT / 4];
  if (bt >= nt) return;
  int e = meta[MO_TILEE / 4 + bt];
  int rb = meta[MO_TILERB / 4 + bt];
  const int* ptok = meta + MO_PTOK / 4;

  __shared__ short sA[2][128 * 32];
  __shared__ short sB[2][128 * 32];
  int tid = threadIdx.x, lane = tid & 63, wid = tid >> 6;
  int wr = wid >> 1, wc = wid & 1;
  int r0 = tid >> 2;
  int c0 = (((tid & 3) ^ ((r0 >> 1) & 3)) << 3);   // swizzled source granule
  int tok0 = ptok[rb + r0];
  int tok1 = ptok[rb + r0 + 64];
  const u16* gA0 = Xb + (size_t)tok0 * D_DIM + c0;
  const u16* gA1 = Xb + (size_t)tok1 * D_DIM + c0;
  const u16* gB0 = W1T + ((size_t)e * F_DIM + cb + r0) * D_DIM + c0;
  const u16* gB1 = gB0 + (size_t)64 * D_DIM;

#define STAGE_G1(buf, k0)                                              \
  {                                                                    \
    gload16(gA0 + (k0), (char*)&sA[buf][0] + wid * 1024);              \
    gload16(gA1 + (k0), (char*)&sA[buf][0] + 4096 + wid * 1024);       \
    gload16(gB0 + (k0), (char*)&sB[buf][0] + wid * 1024);              \
    gload16(gB1 + (k0), (char*)&sB[buf][0] + 4096 + wid * 1024);       \
  }

  f32x4 acc[4][4] = {};
  int kb = (((lane >> 4) ^ (((lane & 15) >> 1) & 3)) << 3);  // swizzled read granule
  int ra = wr * 64 + (lane & 15);
  int rn = wc * 64 + (lane & 15);
  STAGE_G1(0, 0)
  for (int k0 = 0; k0 < D_DIM; k0 += 32) {
    int c = (k0 >> 5) & 1;
    asm volatile("s_waitcnt vmcnt(0) lgkmcnt(0)" ::: "memory");
    __builtin_amdgcn_sched_barrier(0);
    __builtin_amdgcn_s_barrier();
    if (k0 + 32 < D_DIM) STAGE_G1(c ^ 1, k0 + 32)
    const short* pA = &sA[c][0];
    const short* pB = &sB[c][0];
    bf16x8 af[4], bfr[4];
#pragma unroll
    for (int m = 0; m < 4; m++)
      af[m] = *(const bf16x8*)((const char*)pA + ((ra + m * 16) * 32 + kb) * 2);
#pragma unroll
    for (int n = 0; n < 4; n++)
      bfr[n] = *(const bf16x8*)((const char*)pB + ((rn + n * 16) * 32 + kb) * 2);
    __builtin_amdgcn_s_setprio(1);
#pragma unroll
    for (int m = 0; m < 4; m++)
#pragma unroll
      for (int n = 0; n < 4; n++)
        acc[m][n] = __builtin_amdgcn_mfma_f32_16x16x32_bf16(af[m], bfr[n], acc[m][n], 0, 0, 0);
    __builtin_amdgcn_s_setprio(0);
  }
  int rbase = wr * 64 + ((lane >> 4) << 2);
  int cbase = cb + wc * 64 + (lane & 15);
#pragma unroll
  for (int m = 0; m < 4; m++)
#pragma unroll
    for (int n = 0; n < 4; n++) {
      int f = cbase + n * 16;
      float bias = b1[e * F_DIM + f];
#pragma unroll
      for (int r = 0; r < 4; r++) {
        int p = rb + rbase + m * 16 + r;
        float v = acc[m][n][r] + bias;
        float s = v * (1.0f / (1.0f + __expf(-v)));
        H[(size_t)p * F_DIM + f] = f2bf(s);
      }
    }
}

// ---------------- GEMM2: Y = h @ W2[e] + b2[e] ----------------
// 1-D grid 1088 = 8 XCD x 136 (= 17 bt x 8 cb-minor): one row tile's 8
// col blocks co-resident on an XCD -> H strip (1MB) L2-shared.
__global__ __launch_bounds__(256) void gemm2(
    const u16* __restrict__ H, const u16* __restrict__ W2T,
    const float* __restrict__ b2, u16* __restrict__ Y, const int* __restrict__ meta) {
  int id = blockIdx.x;
  int wg = (id & 7) * 136 + (id >> 3);   // bijective, 1088 = 8*136
  int bt = wg >> 3;
  int cb = (wg & 7) * 128;
  int nt = meta[MO_NT / 4];
  if (bt >= nt) return;
  int e = meta[MO_TILEE / 4 + bt];
  int rb = meta[MO_TILERB / 4 + bt];
  __shared__ short sA[2][128 * 32];
  __shared__ short sB[2][128 * 32];
  int tid = threadIdx.x, lane = tid & 63, wid = tid >> 6;
  int wr = wid >> 1, wc = wid & 1;
  int r0 = tid >> 2;
  int c0 = (((tid & 3) ^ ((r0 >> 1) & 3)) << 3);   // swizzled source granule
  const u16* gA0 = H + (size_t)(rb + r0) * F_DIM + c0;
  const u16* gA1 = gA0 + (size_t)64 * F_DIM;
  const u16* gB0 = W2T + ((size_t)e * D_DIM + cb + r0) * F_DIM + c0;
  const u16* gB1 = gB0 + (size_t)64 * F_DIM;

#define STAGE_G2(buf, k0)                                              \
  {                                                                    \
    gload16(gA0 + (k0), (char*)&sA[buf][0] + wid * 1024);              \
    gload16(gA1 + (k0), (char*)&sA[buf][0] + 4096 + wid * 1024);       \
    gload16(gB0 + (k0), (char*)&sB[buf][0] + wid * 1024);              \
    gload16(gB1 + (k0), (char*)&sB[buf][0] + 4096 + wid * 1024);       \
  }

  f32x4 acc[4][4] = {};
  int kb = (((lane >> 4) ^ (((lane & 15) >> 1) & 3)) << 3);  // swizzled read granule
  int ra = wr * 64 + (lane & 15);
  int rn = wc * 64 + (lane & 15);
  STAGE_G2(0, 0)
  for (int k0 = 0; k0 < F_DIM; k0 += 32) {
    int c = (k0 >> 5) & 1;
    asm volatile("s_waitcnt vmcnt(0) lgkmcnt(0)" ::: "memory");
    __builtin_amdgcn_sched_barrier(0);
    __builtin_amdgcn_s_barrier();
    if (k0 + 32 < F_DIM) STAGE_G2(c ^ 1, k0 + 32)
    const short* pA = &sA[c][0];
    const short* pB = &sB[c][0];
    bf16x8 af[4], bfr[4];
#pragma unroll
    for (int m = 0; m < 4; m++)
      af[m] = *(const bf16x8*)((const char*)pA + ((ra + m * 16) * 32 + kb) * 2);
#pragma unroll
    for (int n = 0; n < 4; n++)
      bfr[n] = *(const bf16x8*)((const char*)pB + ((rn + n * 16) * 32 + kb) * 2);
    __builtin_amdgcn_s_setprio(1);
#pragma unroll
    for (int m = 0; m < 4; m++)
#pragma unroll
      for (int n = 0; n < 4; n++)
        acc[m][n] = __builtin_amdgcn_mfma_f32_16x16x32_bf16(af[m], bfr[n], acc[m][n], 0, 0, 0);
    __builtin_amdgcn_s_setprio(0);
  }
  int rbase = wr * 64 + ((lane >> 4) << 2);
  int cbase = cb + wc * 64 + (lane & 15);
#pragma unroll
  for (int m = 0; m < 4; m++)
#pragma unroll
    for (int n = 0; n < 4; n++) {
      int d = cbase + n * 16;
      float bias = b2[e * D_DIM + d];
#pragma unroll
      for (int r = 0; r < 4; r++) {
        int p = rb + rbase + m * 16 + r;
        Y[(size_t)p * D_DIM + d] = f2bf(acc[m][n][r] + bias);
      }
    }
}

// ---------------- combine: out[t] = w1*Y[s1] + w2*Y[s2] ----------------
__global__ __launch_bounds__(256) void combine(const u16* __restrict__ Y,
                                               const int* __restrict__ meta,
                                               float* __restrict__ out) {
  int t = blockIdx.x;
  const int* ts = meta + MO_TSLOT / 4;
  const float* rw = (const float*)meta + MO_ROUTEW / 4;
  int s1 = ts[2 * t], s2 = ts[2 * t + 1];
  float w1 = rw[2 * t], w2 = rw[2 * t + 1];
  int d0 = threadIdx.x * 4;
  ushort4 a = *(const ushort4*)(Y + (size_t)s1 * D_DIM + d0);
  ushort4 b = *(const ushort4*)(Y + (size_t)s2 * D_DIM + d0);
  float4 v;
  v.x = w1 * bf2f(a.x) + w2 * bf2f(b.x);
  v.y = w1 * bf2f(a.y) + w2 * bf2f(b.y);
  v.z = w1 * bf2f(a.z) + w2 * bf2f(b.z);
  v.w = w1 * bf2f(a.w) + w2 * bf2f(b.w);
  *(float4*)(out + (size_t)t * D_DIM + d0) = v;
}

// ---------------- launch ----------------
extern "C" void kernel_launch(void* const* d_in, const int* in_sizes, int n_in,
                              void* d_out, int out_size, void* d_ws, size_t ws_size,
                              hipStream_t stream) {
  (void)in_sizes; (void)n_in; (void)out_size; (void)ws_size;
  const float* X    = (const float*)d_in[0];
  const float* TP   = (const float*)d_in[1];
  const float* Wg   = (const float*)d_in[2];
  const float* bg   = (const float*)d_in[3];
  const float* Wt   = (const float*)d_in[4];
  const float* bgt  = (const float*)d_in[5];
  const float* alp  = (const float*)d_in[6];
  const float* W1   = (const float*)d_in[7];
  const float* b1   = (const float*)d_in[8];
  const float* W2   = (const float*)d_in[9];
  const float* b2   = (const float*)d_in[10];
  float* out = (float*)d_out;
  char* ws = (char*)d_ws;
  u16* Xb = (u16*)(ws + A_XB);
  u16* WT = (u16*)(ws + A_WT);
  u16* H  = (u16*)(ws + A_H);
  u16* Y  = (u16*)(ws + A_Y);
  int* meta = (int*)(ws + A_META);

  zerok<<<(META_INTS + 255) / 256, 256, 0, stream>>>(meta, META_INTS);
  tcvt<<<dim3(F_DIM / 32, D_DIM / 32, E_EXP), 256, 0, stream>>>(W1, WT, D_DIM, F_DIM); // W1T [F][D]
  gating<<<GBLK, 256, 0, stream>>>(X, TP, Wg, bg, Wt, bgt, alp, Xb, meta);
  plan<<<1, 64, 0, stream>>>(meta, out);
  fillk<<<T_TOK / 256, 256, 0, stream>>>(meta);
  gemm1<<<4352, 256, 0, stream>>>(Xb, WT, b1, H, meta);
  tcvt<<<dim3(D_DIM / 32, F_DIM / 32, E_EXP), 256, 0, stream>>>(W2, WT, F_DIM, D_DIM); // W2T [D][F]
  gemm2<<<1088, 256, 0, stream>>>(H, WT, b2, Y, meta);
  combine<<<T_TOK, 256, 0, stream>>>(Y, meta, out);
}

// Round 9
// 567.509 us; speedup vs baseline: 1.4007x; 1.0364x over previous
//
#include <hip/hip_runtime.h>

// ---------------- problem constants ----------------
#define T_TOK 8192      // B*S tokens
#define D_DIM 1024
#define F_DIM 4096
#define E_EXP 8
#define DT_DIM 256
#define GBLK 256        // gating blocks (32 tokens each)

// ---------------- workspace layout (bytes) ----------------
#define A_XB   0u                    // bf16 X   [8192][1024]   16,777,216
#define A_WT   16777216u             // bf16 W1T (and W2T in small-ws mode)
#define A_H    83886080u             // bf16 h   [17408][4096] 142,606,336
#define A_Y    226492416u            // bf16 Y   [17408][1024]  35,651,584
#define A_META 262144000u
#define A_W2T  262428928u            // optional separate W2T (needs ws >= ~330MB)
#define W2T_NEED (262428928ull + 67108864ull)
// meta byte offsets
#define MO_FILL   0        // 8 ints (atomic fill cursors)
#define MO_PB     64       // 9 ints (expert segment bases)
#define MO_NT     128      // 1 int
#define MO_PARTP  256      // f32[256][8] per-block prob partials (8KB)
#define MO_PARTC  8448     // int[256][8] per-block count partials (8KB)
#define MO_TILEE  16640    // int[160]
#define MO_TILERB 17664    // int[160]
#define MO_ROUTEE 18688    // int[16384]
#define MO_ROUTEW 84224    // f32[16384]
#define MO_TSLOT  149760   // int[16384]
#define MO_PTOK   215296   // int[17408]
#define META_BYTES 284928

using bf16x8 = __attribute__((ext_vector_type(8))) short;
using f32x4  = __attribute__((ext_vector_type(4))) float;
typedef unsigned short u16;

__device__ __forceinline__ u16 f2bf(float f) {
  union { float f; unsigned u; } v; v.f = f;
  unsigned r = v.u + 0x7FFFu + ((v.u >> 16) & 1u);   // RNE
  return (u16)(r >> 16);
}
__device__ __forceinline__ float bf2f(u16 h) {
  union { unsigned u; float f; } v; v.u = ((unsigned)h) << 16; return v.f;
}
__device__ __forceinline__ void gload16(const void* gsrc, void* ldst) {
  __builtin_amdgcn_global_load_lds(
      (const __attribute__((address_space(1))) void*)gsrc,
      (__attribute__((address_space(3))) void*)ldst, 16, 0, 0);
}

// ---------------- 64x64 transpose+convert body (vectorized) ----------------
// src [e][R][C] f32 -> dst [e][C][R] bf16; tile (rb, cb). LDS = smem (8.4KB).
__device__ __forceinline__ void tcvt64_body(const float* __restrict__ src,
                                            u16* __restrict__ dst, int R, int C,
                                            int e, int rb, int cb, char* smem) {
  u16 (*tile)[65] = (u16(*)[65])smem;
  size_t off = (size_t)e * R * C;
  int t = threadIdx.x;
  int r = t >> 4, cq = (t & 15) << 2;
#pragma unroll
  for (int k = 0; k < 4; k++) {
    int rr = r + k * 16;
    float4 v = *(const float4*)(src + off + (size_t)(rb + rr) * C + cb + cq);
    tile[rr][cq] = f2bf(v.x);
    tile[rr][cq + 1] = f2bf(v.y);
    tile[rr][cq + 2] = f2bf(v.z);
    tile[rr][cq + 3] = f2bf(v.w);
  }
  __syncthreads();
  int r4 = (t & 15) << 2, c0 = t >> 4;
#pragma unroll
  for (int j = 0; j < 4; j++) {
    int c = c0 + j * 16;
    ushort4 o;
    o.x = tile[r4][c]; o.y = tile[r4 + 1][c];
    o.z = tile[r4 + 2][c]; o.w = tile[r4 + 3][c];
    *(ushort4*)(dst + off + (size_t)(cb + c) * R + rb + r4) = o;
  }
}

// ---------------- prep: fused gating + W1-tcvt (+ W2-tcvt if room) --------
// grid = GBLK + 8192 (+ 8192). blocks [0,GBLK): gating; next 8192: W1; next: W2.
__global__ __launch_bounds__(256) void prep(
    const float* __restrict__ X, const float* __restrict__ TP,
    const float* __restrict__ Wg, const float* __restrict__ bg,
    const float* __restrict__ Wt, const float* __restrict__ bgt,
    const float* __restrict__ alphaP,
    const float* __restrict__ W1, const float* __restrict__ W2,
    u16* __restrict__ Xb, u16* __restrict__ W1T, u16* __restrict__ W2T,
    int* meta) {
  __shared__ char smem[41216];
  int bid = blockIdx.x;
  if (bid >= GBLK) {
    int loc = bid - GBLK;
    if (loc < 8192) {   // W1 [e][1024][4096] -> W1T [e][4096][1024]
      int e = loc >> 10, t10 = loc & 1023;
      tcvt64_body(W1, W1T, D_DIM, F_DIM, e, (t10 & 15) << 6, (t10 >> 4) << 6, smem);
    } else {            // W2 [e][4096][1024] -> W2T [e][1024][4096]
      int l2 = loc - 8192;
      int e = l2 >> 10, t10 = l2 & 1023;
      tcvt64_body(W2, W2T, F_DIM, D_DIM, e, (t10 >> 4) << 6, (t10 & 15) << 6, smem);
    }
    return;
  }
  // ---- gating (32 tokens/block, no atomics) ----
  float* WgT = (float*)smem;                    // [e][d] 32KB
  float* WtT = (float*)(smem + 32768);          // 8KB
  float* wsP = (float*)(smem + 40960);          // [4][8]
  int*   wsC = (int*)(smem + 41088);            // [4][8]
  int tid = threadIdx.x;
  for (int i = tid; i < E_EXP * D_DIM; i += 256) { int d = i >> 3, e = i & 7; WgT[e * D_DIM + d] = Wg[i]; }
  for (int i = tid; i < E_EXP * DT_DIM; i += 256) { int d = i >> 3, e = i & 7; WtT[e * DT_DIM + d] = Wt[i]; }
  __syncthreads();
  int lane = tid & 63, wid = tid >> 6;
  int tb = bid * 32;
  int b = tb >> 11;  // S=2048
  float alpha = alphaP[0];

  float tac[8] = {};
#pragma unroll
  for (int i = 0; i < 4; i++) {
    int d = lane + i * 64;
    float x = TP[b * DT_DIM + d];
#pragma unroll
    for (int e = 0; e < 8; e++) tac[e] += x * WtT[e * DT_DIM + d];
  }
  for (int off = 32; off > 0; off >>= 1)
#pragma unroll
    for (int e = 0; e < 8; e++) tac[e] += __shfl_xor(tac[e], off);
  float tl[8];
#pragma unroll
  for (int e = 0; e < 8; e++) tl[e] = alpha * (tac[e] + bgt[e]);

  float psum[8] = {};
  int   cnt[8] = {};
  for (int i = 0; i < 8; i++) {
    int t = tb + wid * 8 + i;
    const float* xr = X + (size_t)t * D_DIM;
    float acc[8] = {};
    u16 xb[16];
#pragma unroll 4
    for (int j = 0; j < 16; j++) {
      int d = lane + j * 64;
      float x = xr[d];
      xb[j] = f2bf(x);
#pragma unroll
      for (int e = 0; e < 8; e++) acc[e] += x * WgT[e * D_DIM + d];
    }
#pragma unroll
    for (int j = 0; j < 16; j++) Xb[(size_t)t * D_DIM + lane + j * 64] = xb[j];
    for (int off = 32; off > 0; off >>= 1)
#pragma unroll
      for (int e = 0; e < 8; e++) acc[e] += __shfl_xor(acc[e], off);
    float gl[8];
#pragma unroll
    for (int e = 0; e < 8; e++) gl[e] = (1.f - alpha) * (acc[e] + bg[e]) + tl[e];
    int e1 = 0;
#pragma unroll
    for (int e = 1; e < 8; e++) if (gl[e] > gl[e1]) e1 = e;
    int es = (e1 == 0) ? 1 : 0;
#pragma unroll
    for (int e = 0; e < 8; e++) if (e != e1 && gl[e] > gl[es]) es = e;
    float mx = gl[0];
#pragma unroll
    for (int e = 1; e < 8; e++) mx = fmaxf(mx, gl[e]);
    float pe[8], se = 0.f;
#pragma unroll
    for (int e = 0; e < 8; e++) { pe[e] = __expf(gl[e] - mx); se += pe[e]; }
    float inv = 1.f / se;
    if (lane == 0) {
#pragma unroll
      for (int e = 0; e < 8; e++) psum[e] += pe[e] * inv;
      cnt[e1]++; cnt[es]++;
      float w1 = 1.f / (1.f + __expf(gl[es] - gl[e1]));
      meta[MO_ROUTEE / 4 + 2 * t] = e1;
      meta[MO_ROUTEE / 4 + 2 * t + 1] = es;
      ((float*)meta)[MO_ROUTEW / 4 + 2 * t] = w1;
      ((float*)meta)[MO_ROUTEW / 4 + 2 * t + 1] = 1.f - w1;
    }
  }
  if (lane == 0) {
#pragma unroll
    for (int e = 0; e < 8; e++) { wsP[wid * 8 + e] = psum[e]; wsC[wid * 8 + e] = cnt[e]; }
  }
  __syncthreads();
  if (tid < 8) {
    float p = wsP[tid] + wsP[8 + tid] + wsP[16 + tid] + wsP[24 + tid];
    int   c = wsC[tid] + wsC[8 + tid] + wsC[16 + tid] + wsC[24 + tid];
    ((float*)meta)[MO_PARTP / 4 + bid * 8 + tid] = p;
    meta[MO_PARTC / 4 + bid * 8 + tid] = c;
  }
}

// ---------------- standalone W2 tcvt (small-ws fallback, into WT) ----------
__global__ __launch_bounds__(256) void tcvt2k(const float* __restrict__ W2,
                                              u16* __restrict__ W2T) {
  __shared__ char smem[8448];
  int loc = blockIdx.x;
  int e = loc >> 10, t10 = loc & 1023;
  tcvt64_body(W2, W2T, F_DIM, D_DIM, e, (t10 >> 4) << 6, (t10 & 15) << 6, smem);
}

// ---------------- plan: reduce, bases, tile map, l_aux, init fills --------
__global__ void plan(int* meta, float* out) {
  __shared__ float sp[8];
  __shared__ int   sc[8];
  int tid = threadIdx.x;
  if (blockIdx.x != 0) return;
  if (tid < 8) {
    const float* pp = (const float*)meta + MO_PARTP / 4;
    const int*   pc = meta + MO_PARTC / 4;
    float p = 0.f; int c = 0;
    for (int b = 0; b < GBLK; b++) { p += pp[b * 8 + tid]; c += pc[b * 8 + tid]; }
    sp[tid] = p; sc[tid] = c;
    meta[MO_FILL / 4 + tid] = 0;            // reset fill cursors (zerok dropped)
  }
  // default-fill ptok so padded slots gather a valid token (0)
  int* ptok = meta + MO_PTOK / 4;
  for (int i = tid; i < 17408; i += 64) ptok[i] = 0;
  __syncthreads();
  if (tid == 0) {
    int* pb = meta + MO_PB / 4;
    int* tileE = meta + MO_TILEE / 4;
    int* tileRB = meta + MO_TILERB / 4;
    int base = 0, nt = 0;
    float la = 0.f;
    for (int e = 0; e < 8; e++) {
      int n = sc[e];
      pb[e] = base;
      int ntl = (n + 127) >> 7;
      for (int i = 0; i < ntl; i++) { tileE[nt] = e; tileRB[nt] = base + (i << 7); nt++; }
      base += ntl << 7;
      la += (sp[e] * (1.f / 8192.f)) * ((float)n * (1.f / 8192.f));
    }
    pb[8] = base;
    meta[MO_NT / 4] = nt;
    out[T_TOK * D_DIM] = la;  // l_aux
  }
}

// ---------------- fill slot lists (wave-aggregated atomics) ----------------
__global__ __launch_bounds__(256) void fillk(int* meta) {
  int t = blockIdx.x * 256 + threadIdx.x;
  int lane = threadIdx.x & 63;
  int* pb = meta + MO_PB / 4;
  int* fl = meta + MO_FILL / 4;
  int* ptok = meta + MO_PTOK / 4;
  int* ts = meta + MO_TSLOT / 4;
  unsigned long long lmask = (1ull << lane) - 1;  // lanes below
#pragma unroll
  for (int k = 0; k < 2; k++) {
    int e = meta[MO_ROUTEE / 4 + 2 * t + k];
    int slot = 0;
    for (int ee = 0; ee < 8; ee++) {
      unsigned long long mask = __ballot(e == ee);
      if (e == ee) {
        int low = __ffsll((long long)mask) - 1;
        int pre = __popcll(mask & lmask);
        int base = 0;
        if (lane == low) base = atomicAdd(&fl[ee], __popcll(mask));
        base = __shfl(base, low);
        slot = pb[ee] + base + pre;
      }
    }
    ptok[slot] = t;
    ts[2 * t + k] = slot;
  }
}

// =====================================================================
// GEMM core (r8, unchanged): 128x128 tile, BK=32, double-buffered 32KB
// LDS, 256 thr, 4 waves x 64x64. One s_barrier per K-step; stage(k+1)
// after the barrier; wait at next iteration's top. T2 XOR swizzle.
// =====================================================================

// ---------------- GEMM1: h = silu(X[tok] @ W1[e] + b1[e]) ----------------
__global__ __launch_bounds__(256) void gemm1(
    const u16* __restrict__ Xb, const u16* __restrict__ W1T,
    const float* __restrict__ b1, u16* __restrict__ H, const int* __restrict__ meta) {
  int xcd = blockIdx.x & 7, loc = blockIdx.x >> 3;   // 4352 = 8*544
  int bt = loc >> 2;
  int cb = (xcd * 4 + (loc & 3)) * 128;
  int nt = meta[MO_NT / 4];
  if (bt >= nt) return;
  int e = meta[MO_TILEE / 4 + bt];
  int rb = meta[MO_TILERB / 4 + bt];
  const int* ptok = meta + MO_PTOK / 4;

  __shared__ short sA[2][128 * 32];
  __shared__ short sB[2][128 * 32];
  int tid = threadIdx.x, lane = tid & 63, wid = tid >> 6;
  int wr = wid >> 1, wc = wid & 1;
  int r0 = tid >> 2;
  int c0 = (((tid & 3) ^ ((r0 >> 1) & 3)) << 3);   // swizzled source granule
  int tok0 = ptok[rb + r0];
  int tok1 = ptok[rb + r0 + 64];
  const u16* gA0 = Xb + (size_t)tok0 * D_DIM + c0;
  const u16* gA1 = Xb + (size_t)tok1 * D_DIM + c0;
  const u16* gB0 = W1T + ((size_t)e * F_DIM + cb + r0) * D_DIM + c0;
  const u16* gB1 = gB0 + (size_t)64 * D_DIM;

#define STAGE_G1(buf, k0)                                              \
  {                                                                    \
    gload16(gA0 + (k0), (char*)&sA[buf][0] + wid * 1024);              \
    gload16(gA1 + (k0), (char*)&sA[buf][0] + 4096 + wid * 1024);       \
    gload16(gB0 + (k0), (char*)&sB[buf][0] + wid * 1024);              \
    gload16(gB1 + (k0), (char*)&sB[buf][0] + 4096 + wid * 1024);       \
  }

  f32x4 acc[4][4] = {};
  int kb = (((lane >> 4) ^ (((lane & 15) >> 1) & 3)) << 3);  // swizzled read granule
  int ra = wr * 64 + (lane & 15);
  int rn = wc * 64 + (lane & 15);
  STAGE_G1(0, 0)
  for (int k0 = 0; k0 < D_DIM; k0 += 32) {
    int c = (k0 >> 5) & 1;
    asm volatile("s_waitcnt vmcnt(0) lgkmcnt(0)" ::: "memory");
    __builtin_amdgcn_sched_barrier(0);
    __builtin_amdgcn_s_barrier();
    if (k0 + 32 < D_DIM) STAGE_G1(c ^ 1, k0 + 32)
    const short* pA = &sA[c][0];
    const short* pB = &sB[c][0];
    bf16x8 af[4], bfr[4];
#pragma unroll
    for (int m = 0; m < 4; m++)
      af[m] = *(const bf16x8*)((const char*)pA + ((ra + m * 16) * 32 + kb) * 2);
#pragma unroll
    for (int n = 0; n < 4; n++)
      bfr[n] = *(const bf16x8*)((const char*)pB + ((rn + n * 16) * 32 + kb) * 2);
    __builtin_amdgcn_s_setprio(1);
#pragma unroll
    for (int m = 0; m < 4; m++)
#pragma unroll
      for (int n = 0; n < 4; n++)
        acc[m][n] = __builtin_amdgcn_mfma_f32_16x16x32_bf16(af[m], bfr[n], acc[m][n], 0, 0, 0);
    __builtin_amdgcn_s_setprio(0);
  }
  int rbase = wr * 64 + ((lane >> 4) << 2);
  int cbase = cb + wc * 64 + (lane & 15);
#pragma unroll
  for (int m = 0; m < 4; m++)
#pragma unroll
    for (int n = 0; n < 4; n++) {
      int f = cbase + n * 16;
      float bias = b1[e * F_DIM + f];
#pragma unroll
      for (int r = 0; r < 4; r++) {
        int p = rb + rbase + m * 16 + r;
        float v = acc[m][n][r] + bias;
        float s = v * (1.0f / (1.0f + __expf(-v)));
        H[(size_t)p * F_DIM + f] = f2bf(s);
      }
    }
}

// ---------------- GEMM2: Y = h @ W2[e] + b2[e] ----------------
__global__ __launch_bounds__(256) void gemm2(
    const u16* __restrict__ H, const u16* __restrict__ W2T,
    const float* __restrict__ b2, u16* __restrict__ Y, const int* __restrict__ meta) {
  int id = blockIdx.x;
  int wg = (id & 7) * 136 + (id >> 3);   // bijective, 1088 = 8*136
  int bt = wg >> 3;
  int cb = (wg & 7) * 128;
  int nt = meta[MO_NT / 4];
  if (bt >= nt) return;
  int e = meta[MO_TILEE / 4 + bt];
  int rb = meta[MO_TILERB / 4 + bt];
  __shared__ short sA[2][128 * 32];
  __shared__ short sB[2][128 * 32];
  int tid = threadIdx.x, lane = tid & 63, wid = tid >> 6;
  int wr = wid >> 1, wc = wid & 1;
  int r0 = tid >> 2;
  int c0 = (((tid & 3) ^ ((r0 >> 1) & 3)) << 3);   // swizzled source granule
  const u16* gA0 = H + (size_t)(rb + r0) * F_DIM + c0;
  const u16* gA1 = gA0 + (size_t)64 * F_DIM;
  const u16* gB0 = W2T + ((size_t)e * D_DIM + cb + r0) * F_DIM + c0;
  const u16* gB1 = gB0 + (size_t)64 * F_DIM;

#define STAGE_G2(buf, k0)                                              \
  {                                                                    \
    gload16(gA0 + (k0), (char*)&sA[buf][0] + wid * 1024);              \
    gload16(gA1 + (k0), (char*)&sA[buf][0] + 4096 + wid * 1024);       \
    gload16(gB0 + (k0), (char*)&sB[buf][0] + wid * 1024);              \
    gload16(gB1 + (k0), (char*)&sB[buf][0] + 4096 + wid * 1024);       \
  }

  f32x4 acc[4][4] = {};
  int kb = (((lane >> 4) ^ (((lane & 15) >> 1) & 3)) << 3);  // swizzled read granule
  int ra = wr * 64 + (lane & 15);
  int rn = wc * 64 + (lane & 15);
  STAGE_G2(0, 0)
  for (int k0 = 0; k0 < F_DIM; k0 += 32) {
    int c = (k0 >> 5) & 1;
    asm volatile("s_waitcnt vmcnt(0) lgkmcnt(0)" ::: "memory");
    __builtin_amdgcn_sched_barrier(0);
    __builtin_amdgcn_s_barrier();
    if (k0 + 32 < F_DIM) STAGE_G2(c ^ 1, k0 + 32)
    const short* pA = &sA[c][0];
    const short* pB = &sB[c][0];
    bf16x8 af[4], bfr[4];
#pragma unroll
    for (int m = 0; m < 4; m++)
      af[m] = *(const bf16x8*)((const char*)pA + ((ra + m * 16) * 32 + kb) * 2);
#pragma unroll
    for (int n = 0; n < 4; n++)
      bfr[n] = *(const bf16x8*)((const char*)pB + ((rn + n * 16) * 32 + kb) * 2);
    __builtin_amdgcn_s_setprio(1);
#pragma unroll
    for (int m = 0; m < 4; m++)
#pragma unroll
      for (int n = 0; n < 4; n++)
        acc[m][n] = __builtin_amdgcn_mfma_f32_16x16x32_bf16(af[m], bfr[n], acc[m][n], 0, 0, 0);
    __builtin_amdgcn_s_setprio(0);
  }
  int rbase = wr * 64 + ((lane >> 4) << 2);
  int cbase = cb + wc * 64 + (lane & 15);
#pragma unroll
  for (int m = 0; m < 4; m++)
#pragma unroll
    for (int n = 0; n < 4; n++) {
      int d = cbase + n * 16;
      float bias = b2[e * D_DIM + d];
#pragma unroll
      for (int r = 0; r < 4; r++) {
        int p = rb + rbase + m * 16 + r;
        Y[(size_t)p * D_DIM + d] = f2bf(acc[m][n][r] + bias);
      }
    }
}

// ---------------- combine: out[t] = w1*Y[s1] + w2*Y[s2] ----------------
__global__ __launch_bounds__(256) void combine(const u16* __restrict__ Y,
                                               const int* __restrict__ meta,
                                               float* __restrict__ out) {
  int t = blockIdx.x;
  const int* ts = meta + MO_TSLOT / 4;
  const float* rw = (const float*)meta + MO_ROUTEW / 4;
  int s1 = ts[2 * t], s2 = ts[2 * t + 1];
  float w1 = rw[2 * t], w2 = rw[2 * t + 1];
  int d0 = threadIdx.x * 4;
  ushort4 a = *(const ushort4*)(Y + (size_t)s1 * D_DIM + d0);
  ushort4 b = *(const ushort4*)(Y + (size_t)s2 * D_DIM + d0);
  float4 v;
  v.x = w1 * bf2f(a.x) + w2 * bf2f(b.x);
  v.y = w1 * bf2f(a.y) + w2 * bf2f(b.y);
  v.z = w1 * bf2f(a.z) + w2 * bf2f(b.z);
  v.w = w1 * bf2f(a.w) + w2 * bf2f(b.w);
  *(float4*)(out + (size_t)t * D_DIM + d0) = v;
}

// ---------------- launch ----------------
extern "C" void kernel_launch(void* const* d_in, const int* in_sizes, int n_in,
                              void* d_out, int out_size, void* d_ws, size_t ws_size,
                              hipStream_t stream) {
  (void)in_sizes; (void)n_in; (void)out_size;
  const float* X    = (const float*)d_in[0];
  const float* TP   = (const float*)d_in[1];
  const float* Wg   = (const float*)d_in[2];
  const float* bg   = (const float*)d_in[3];
  const float* Wt   = (const float*)d_in[4];
  const float* bgt  = (const float*)d_in[5];
  const float* alp  = (const float*)d_in[6];
  const float* W1   = (const float*)d_in[7];
  const float* b1   = (const float*)d_in[8];
  const float* W2   = (const float*)d_in[9];
  const float* b2   = (const float*)d_in[10];
  float* out = (float*)d_out;
  char* ws = (char*)d_ws;
  u16* Xb = (u16*)(ws + A_XB);
  u16* WT = (u16*)(ws + A_WT);
  u16* H  = (u16*)(ws + A_H);
  u16* Y  = (u16*)(ws + A_Y);
  int* meta = (int*)(ws + A_META);

  int big = ws_size >= W2T_NEED;               // room for separate W2T?
  u16* W2T = big ? (u16*)(ws + A_W2T) : WT;

  int prep_grid = GBLK + 8192 + (big ? 8192 : 0);
  prep<<<prep_grid, 256, 0, stream>>>(X, TP, Wg, bg, Wt, bgt, alp, W1, W2,
                                      Xb, WT, W2T, meta);
  plan<<<1, 64, 0, stream>>>(meta, out);
  fillk<<<T_TOK / 256, 256, 0, stream>>>(meta);
  gemm1<<<4352, 256, 0, stream>>>(Xb, WT, b1, H, meta);
  if (!big) tcvt2k<<<8192, 256, 0, stream>>>(W2, WT);  // overwrite W1T after gemm1
  gemm2<<<1088, 256, 0, stream>>>(H, W2T, b2, Y, meta);
  combine<<<T_TOK, 256, 0, stream>>>(Y, meta, out);
}

// Round 10
// 553.078 us; speedup vs baseline: 1.4373x; 1.0261x over previous
//
#include <hip/hip_runtime.h>

// ---------------- problem constants ----------------
#define T_TOK 8192      // B*S tokens
#define D_DIM 1024
#define F_DIM 4096
#define E_EXP 8
#define DT_DIM 256
#define GBLK 256        // gating blocks (32 tokens each)

// ---------------- workspace layout (bytes) ----------------
#define A_XB   0u                    // bf16 X   [8192][1024]   16,777,216
#define A_WT   16777216u             // bf16 W1T (and W2T in small-ws mode)
#define A_H    83886080u             // bf16 h   [17408][4096] 142,606,336
#define A_Y    226492416u            // bf16 Y   [17408][1024]  35,651,584
#define A_META 262144000u
#define A_W2T  262428928u            // optional separate W2T (needs ws >= ~330MB)
#define W2T_NEED (262428928ull + 67108864ull)
// meta byte offsets
#define MO_FILL   0        // 8 ints (atomic fill cursors)
#define MO_PB     64       // 9 ints (expert segment bases)
#define MO_NT     128      // 1 int
#define MO_PARTP  256      // f32[256][8] per-block prob partials (8KB)
#define MO_PARTC  8448     // int[256][8] per-block count partials (8KB)
#define MO_TILEE  16640    // int[160]
#define MO_TILERB 17664    // int[160]
#define MO_ROUTEE 18688    // int[16384]
#define MO_ROUTEW 84224    // f32[16384]
#define MO_TSLOT  149760   // int[16384]
#define MO_PTOK   215296   // int[17408]
#define META_BYTES 284928

using bf16x8 = __attribute__((ext_vector_type(8))) short;
using f32x4  = __attribute__((ext_vector_type(4))) float;
typedef unsigned short u16;

__device__ __forceinline__ u16 f2bf(float f) {
  union { float f; unsigned u; } v; v.f = f;
  unsigned r = v.u + 0x7FFFu + ((v.u >> 16) & 1u);   // RNE
  return (u16)(r >> 16);
}
__device__ __forceinline__ float bf2f(u16 h) {
  union { unsigned u; float f; } v; v.u = ((unsigned)h) << 16; return v.f;
}
__device__ __forceinline__ void gload16(const void* gsrc, void* ldst) {
  __builtin_amdgcn_global_load_lds(
      (const __attribute__((address_space(1))) void*)gsrc,
      (__attribute__((address_space(3))) void*)ldst, 16, 0, 0);
}

// ---------------- 64x64 transpose+convert body (vectorized) ----------------
// src [e][R][C] f32 -> dst [e][C][R] bf16; tile (rb, cb). smem >= 8320B.
__device__ __forceinline__ void tcvt64_body(const float* __restrict__ src,
                                            u16* __restrict__ dst, int R, int C,
                                            int e, int rb, int cb, char* smem) {
  u16 (*tile)[65] = (u16(*)[65])smem;
  size_t off = (size_t)e * R * C;
  int t = threadIdx.x;
  int r = t >> 4, cq = (t & 15) << 2;
#pragma unroll
  for (int k = 0; k < 4; k++) {
    int rr = r + k * 16;
    float4 v = *(const float4*)(src + off + (size_t)(rb + rr) * C + cb + cq);
    tile[rr][cq] = f2bf(v.x);
    tile[rr][cq + 1] = f2bf(v.y);
    tile[rr][cq + 2] = f2bf(v.z);
    tile[rr][cq + 3] = f2bf(v.w);
  }
  __syncthreads();
  int r4 = (t & 15) << 2, c0 = t >> 4;
#pragma unroll
  for (int j = 0; j < 4; j++) {
    int c = c0 + j * 16;
    ushort4 o;
    o.x = tile[r4][c]; o.y = tile[r4 + 1][c];
    o.z = tile[r4 + 2][c]; o.w = tile[r4 + 3][c];
    *(ushort4*)(dst + off + (size_t)(cb + c) * R + rb + r4) = o;
  }
}

// ---------------- prep: fused gating + W1-tcvt ----------------
// grid = GBLK + 8192. blocks [0,GBLK): gating; next 8192: W1 tcvt.
__global__ __launch_bounds__(256) void prep(
    const float* __restrict__ X, const float* __restrict__ TP,
    const float* __restrict__ Wg, const float* __restrict__ bg,
    const float* __restrict__ Wt, const float* __restrict__ bgt,
    const float* __restrict__ alphaP,
    const float* __restrict__ W1,
    u16* __restrict__ Xb, u16* __restrict__ W1T, int* meta) {
  __shared__ char smem[41216];
  int bid = blockIdx.x;
  if (bid >= GBLK) {
    int loc = bid - GBLK;   // W1 [e][1024][4096] -> W1T [e][4096][1024]
    int e = loc >> 10, t10 = loc & 1023;
    tcvt64_body(W1, W1T, D_DIM, F_DIM, e, (t10 & 15) << 6, (t10 >> 4) << 6, smem);
    return;
  }
  // ---- gating (32 tokens/block, no atomics) ----
  float* WgT = (float*)smem;                    // [e][d] 32KB
  float* WtT = (float*)(smem + 32768);          // 8KB
  float* wsP = (float*)(smem + 40960);          // [4][8]
  int*   wsC = (int*)(smem + 41088);            // [4][8]
  int tid = threadIdx.x;
  for (int i = tid; i < E_EXP * D_DIM; i += 256) { int d = i >> 3, e = i & 7; WgT[e * D_DIM + d] = Wg[i]; }
  for (int i = tid; i < E_EXP * DT_DIM; i += 256) { int d = i >> 3, e = i & 7; WtT[e * DT_DIM + d] = Wt[i]; }
  __syncthreads();
  int lane = tid & 63, wid = tid >> 6;
  int tb = bid * 32;
  int b = tb >> 11;  // S=2048
  float alpha = alphaP[0];

  float tac[8] = {};
#pragma unroll
  for (int i = 0; i < 4; i++) {
    int d = lane + i * 64;
    float x = TP[b * DT_DIM + d];
#pragma unroll
    for (int e = 0; e < 8; e++) tac[e] += x * WtT[e * DT_DIM + d];
  }
  for (int off = 32; off > 0; off >>= 1)
#pragma unroll
    for (int e = 0; e < 8; e++) tac[e] += __shfl_xor(tac[e], off);
  float tl[8];
#pragma unroll
  for (int e = 0; e < 8; e++) tl[e] = alpha * (tac[e] + bgt[e]);

  float psum[8] = {};
  int   cnt[8] = {};
  for (int i = 0; i < 8; i++) {
    int t = tb + wid * 8 + i;
    const float* xr = X + (size_t)t * D_DIM;
    float acc[8] = {};
    u16 xb[16];
#pragma unroll 4
    for (int j = 0; j < 16; j++) {
      int d = lane + j * 64;
      float x = xr[d];
      xb[j] = f2bf(x);
#pragma unroll
      for (int e = 0; e < 8; e++) acc[e] += x * WgT[e * D_DIM + d];
    }
#pragma unroll
    for (int j = 0; j < 16; j++) Xb[(size_t)t * D_DIM + lane + j * 64] = xb[j];
    for (int off = 32; off > 0; off >>= 1)
#pragma unroll
      for (int e = 0; e < 8; e++) acc[e] += __shfl_xor(acc[e], off);
    float gl[8];
#pragma unroll
    for (int e = 0; e < 8; e++) gl[e] = (1.f - alpha) * (acc[e] + bg[e]) + tl[e];
    int e1 = 0;
#pragma unroll
    for (int e = 1; e < 8; e++) if (gl[e] > gl[e1]) e1 = e;
    int es = (e1 == 0) ? 1 : 0;
#pragma unroll
    for (int e = 0; e < 8; e++) if (e != e1 && gl[e] > gl[es]) es = e;
    float mx = gl[0];
#pragma unroll
    for (int e = 1; e < 8; e++) mx = fmaxf(mx, gl[e]);
    float pe[8], se = 0.f;
#pragma unroll
    for (int e = 0; e < 8; e++) { pe[e] = __expf(gl[e] - mx); se += pe[e]; }
    float inv = 1.f / se;
    if (lane == 0) {
#pragma unroll
      for (int e = 0; e < 8; e++) psum[e] += pe[e] * inv;
      cnt[e1]++; cnt[es]++;
      float w1 = 1.f / (1.f + __expf(gl[es] - gl[e1]));
      meta[MO_ROUTEE / 4 + 2 * t] = e1;
      meta[MO_ROUTEE / 4 + 2 * t + 1] = es;
      ((float*)meta)[MO_ROUTEW / 4 + 2 * t] = w1;
      ((float*)meta)[MO_ROUTEW / 4 + 2 * t + 1] = 1.f - w1;
    }
  }
  if (lane == 0) {
#pragma unroll
    for (int e = 0; e < 8; e++) { wsP[wid * 8 + e] = psum[e]; wsC[wid * 8 + e] = cnt[e]; }
  }
  __syncthreads();
  if (tid < 8) {
    float p = wsP[tid] + wsP[8 + tid] + wsP[16 + tid] + wsP[24 + tid];
    int   c = wsC[tid] + wsC[8 + tid] + wsC[16 + tid] + wsC[24 + tid];
    ((float*)meta)[MO_PARTP / 4 + bid * 8 + tid] = p;
    meta[MO_PARTC / 4 + bid * 8 + tid] = c;
  }
}

// ---------------- standalone W2 tcvt (small-ws fallback, into WT) ----------
__global__ __launch_bounds__(256) void tcvt2k(const float* __restrict__ W2,
                                              u16* __restrict__ W2T) {
  __shared__ char smem[8448];
  int loc = blockIdx.x;
  int e = loc >> 10, t10 = loc & 1023;
  tcvt64_body(W2, W2T, F_DIM, D_DIM, e, (t10 >> 4) << 6, (t10 & 15) << 6, smem);
}

// ---------------- plan: reduce, bases, tile map, l_aux, init fills --------
__global__ void plan(int* meta, float* out) {
  __shared__ float sp[8];
  __shared__ int   sc[8];
  int tid = threadIdx.x;
  if (blockIdx.x != 0) return;
  if (tid < 8) {
    const float* pp = (const float*)meta + MO_PARTP / 4;
    const int*   pc = meta + MO_PARTC / 4;
    float p = 0.f; int c = 0;
    for (int b = 0; b < GBLK; b++) { p += pp[b * 8 + tid]; c += pc[b * 8 + tid]; }
    sp[tid] = p; sc[tid] = c;
    meta[MO_FILL / 4 + tid] = 0;            // reset fill cursors
  }
  // default-fill ptok so padded slots gather a valid token (0)
  int* ptok = meta + MO_PTOK / 4;
  for (int i = tid; i < 17408; i += 64) ptok[i] = 0;
  __syncthreads();
  if (tid == 0) {
    int* pb = meta + MO_PB / 4;
    int* tileE = meta + MO_TILEE / 4;
    int* tileRB = meta + MO_TILERB / 4;
    int base = 0, nt = 0;
    float la = 0.f;
    for (int e = 0; e < 8; e++) {
      int n = sc[e];
      pb[e] = base;
      int ntl = (n + 127) >> 7;
      for (int i = 0; i < ntl; i++) { tileE[nt] = e; tileRB[nt] = base + (i << 7); nt++; }
      base += ntl << 7;
      la += (sp[e] * (1.f / 8192.f)) * ((float)n * (1.f / 8192.f));
    }
    pb[8] = base;
    meta[MO_NT / 4] = nt;
    out[T_TOK * D_DIM] = la;  // l_aux
  }
}

// ---------------- fill slot lists (wave-aggregated atomics) ----------------
__global__ __launch_bounds__(256) void fillk(int* meta) {
  int t = blockIdx.x * 256 + threadIdx.x;
  int lane = threadIdx.x & 63;
  int* pb = meta + MO_PB / 4;
  int* fl = meta + MO_FILL / 4;
  int* ptok = meta + MO_PTOK / 4;
  int* ts = meta + MO_TSLOT / 4;
  unsigned long long lmask = (1ull << lane) - 1;  // lanes below
#pragma unroll
  for (int k = 0; k < 2; k++) {
    int e = meta[MO_ROUTEE / 4 + 2 * t + k];
    int slot = 0;
    for (int ee = 0; ee < 8; ee++) {
      unsigned long long mask = __ballot(e == ee);
      if (e == ee) {
        int low = __ffsll((long long)mask) - 1;
        int pre = __popcll(mask & lmask);
        int base = 0;
        if (lane == low) base = atomicAdd(&fl[ee], __popcll(mask));
        base = __shfl(base, low);
        slot = pb[ee] + base + pre;
      }
    }
    ptok[slot] = t;
    ts[2 * t + k] = slot;
  }
}

// =====================================================================
// GEMM core (r8, unchanged): 128x128 tile, BK=32, double-buffered 32KB
// LDS, 256 thr, 4 waves x 64x64. One s_barrier per K-step; stage(k+1)
// after the barrier; wait at next iteration's top. T2 XOR swizzle.
// NEW (big-ws only): blocks >= 4352 of gemm1's grid run the W2
// transpose co-scheduled with the GEMM (fills idle HBM BW); W2T is a
// separate buffer and only read by gemm2 (launched after gemm1 drains).
// =====================================================================

// ---------------- GEMM1 (+ co-scheduled W2 tcvt in big-ws mode) ----------
__global__ __launch_bounds__(256) void gemm1(
    const u16* __restrict__ Xb, const u16* __restrict__ W1T,
    const float* __restrict__ b1, u16* __restrict__ H,
    const float* __restrict__ W2, u16* __restrict__ W2T,
    const int* __restrict__ meta) {
  __shared__ char smem[32768];
  if (blockIdx.x >= 4352) {     // W2 [e][4096][1024] -> W2T [e][1024][4096]
    int loc = blockIdx.x - 4352;
    int e = loc >> 10, t10 = loc & 1023;
    tcvt64_body(W2, W2T, F_DIM, D_DIM, e, (t10 >> 4) << 6, (t10 & 15) << 6, smem);
    return;
  }
  short (*sA)[128 * 32] = (short(*)[128 * 32])smem;              // [2][4096]
  short (*sB)[128 * 32] = (short(*)[128 * 32])(smem + 16384);    // [2][4096]
  int xcd = blockIdx.x & 7, loc = blockIdx.x >> 3;   // 4352 = 8*544
  int bt = loc >> 2;
  int cb = (xcd * 4 + (loc & 3)) * 128;
  int nt = meta[MO_NT / 4];
  if (bt >= nt) return;
  int e = meta[MO_TILEE / 4 + bt];
  int rb = meta[MO_TILERB / 4 + bt];
  const int* ptok = meta + MO_PTOK / 4;

  int tid = threadIdx.x, lane = tid & 63, wid = tid >> 6;
  int wr = wid >> 1, wc = wid & 1;
  int r0 = tid >> 2;
  int c0 = (((tid & 3) ^ ((r0 >> 1) & 3)) << 3);   // swizzled source granule
  int tok0 = ptok[rb + r0];
  int tok1 = ptok[rb + r0 + 64];
  const u16* gA0 = Xb + (size_t)tok0 * D_DIM + c0;
  const u16* gA1 = Xb + (size_t)tok1 * D_DIM + c0;
  const u16* gB0 = W1T + ((size_t)e * F_DIM + cb + r0) * D_DIM + c0;
  const u16* gB1 = gB0 + (size_t)64 * D_DIM;

#define STAGE_G1(buf, k0)                                              \
  {                                                                    \
    gload16(gA0 + (k0), (char*)&sA[buf][0] + wid * 1024);              \
    gload16(gA1 + (k0), (char*)&sA[buf][0] + 4096 + wid * 1024);       \
    gload16(gB0 + (k0), (char*)&sB[buf][0] + wid * 1024);              \
    gload16(gB1 + (k0), (char*)&sB[buf][0] + 4096 + wid * 1024);       \
  }

  f32x4 acc[4][4] = {};
  int kb = (((lane >> 4) ^ (((lane & 15) >> 1) & 3)) << 3);  // swizzled read granule
  int ra = wr * 64 + (lane & 15);
  int rn = wc * 64 + (lane & 15);
  STAGE_G1(0, 0)
  for (int k0 = 0; k0 < D_DIM; k0 += 32) {
    int c = (k0 >> 5) & 1;
    asm volatile("s_waitcnt vmcnt(0) lgkmcnt(0)" ::: "memory");
    __builtin_amdgcn_sched_barrier(0);
    __builtin_amdgcn_s_barrier();
    if (k0 + 32 < D_DIM) STAGE_G1(c ^ 1, k0 + 32)
    const short* pA = &sA[c][0];
    const short* pB = &sB[c][0];
    bf16x8 af[4], bfr[4];
#pragma unroll
    for (int m = 0; m < 4; m++)
      af[m] = *(const bf16x8*)((const char*)pA + ((ra + m * 16) * 32 + kb) * 2);
#pragma unroll
    for (int n = 0; n < 4; n++)
      bfr[n] = *(const bf16x8*)((const char*)pB + ((rn + n * 16) * 32 + kb) * 2);
    __builtin_amdgcn_s_setprio(1);
#pragma unroll
    for (int m = 0; m < 4; m++)
#pragma unroll
      for (int n = 0; n < 4; n++)
        acc[m][n] = __builtin_amdgcn_mfma_f32_16x16x32_bf16(af[m], bfr[n], acc[m][n], 0, 0, 0);
    __builtin_amdgcn_s_setprio(0);
  }
  int rbase = wr * 64 + ((lane >> 4) << 2);
  int cbase = cb + wc * 64 + (lane & 15);
#pragma unroll
  for (int m = 0; m < 4; m++)
#pragma unroll
    for (int n = 0; n < 4; n++) {
      int f = cbase + n * 16;
      float bias = b1[e * F_DIM + f];
#pragma unroll
      for (int r = 0; r < 4; r++) {
        int p = rb + rbase + m * 16 + r;
        float v = acc[m][n][r] + bias;
        float s = v * (1.0f / (1.0f + __expf(-v)));
        H[(size_t)p * F_DIM + f] = f2bf(s);
      }
    }
}

// ---------------- GEMM2: Y = h @ W2[e] + b2[e] ----------------
__global__ __launch_bounds__(256) void gemm2(
    const u16* __restrict__ H, const u16* __restrict__ W2T,
    const float* __restrict__ b2, u16* __restrict__ Y, const int* __restrict__ meta) {
  int id = blockIdx.x;
  int wg = (id & 7) * 136 + (id >> 3);   // bijective, 1088 = 8*136
  int bt = wg >> 3;
  int cb = (wg & 7) * 128;
  int nt = meta[MO_NT / 4];
  if (bt >= nt) return;
  int e = meta[MO_TILEE / 4 + bt];
  int rb = meta[MO_TILERB / 4 + bt];
  __shared__ short sA[2][128 * 32];
  __shared__ short sB[2][128 * 32];
  int tid = threadIdx.x, lane = tid & 63, wid = tid >> 6;
  int wr = wid >> 1, wc = wid & 1;
  int r0 = tid >> 2;
  int c0 = (((tid & 3) ^ ((r0 >> 1) & 3)) << 3);   // swizzled source granule
  const u16* gA0 = H + (size_t)(rb + r0) * F_DIM + c0;
  const u16* gA1 = gA0 + (size_t)64 * F_DIM;
  const u16* gB0 = W2T + ((size_t)e * D_DIM + cb + r0) * F_DIM + c0;
  const u16* gB1 = gB0 + (size_t)64 * F_DIM;

#define STAGE_G2(buf, k0)                                              \
  {                                                                    \
    gload16(gA0 + (k0), (char*)&sA[buf][0] + wid * 1024);              \
    gload16(gA1 + (k0), (char*)&sA[buf][0] + 4096 + wid * 1024);       \
    gload16(gB0 + (k0), (char*)&sB[buf][0] + wid * 1024);              \
    gload16(gB1 + (k0), (char*)&sB[buf][0] + 4096 + wid * 1024);       \
  }

  f32x4 acc[4][4] = {};
  int kb = (((lane >> 4) ^ (((lane & 15) >> 1) & 3)) << 3);  // swizzled read granule
  int ra = wr * 64 + (lane & 15);
  int rn = wc * 64 + (lane & 15);
  STAGE_G2(0, 0)
  for (int k0 = 0; k0 < F_DIM; k0 += 32) {
    int c = (k0 >> 5) & 1;
    asm volatile("s_waitcnt vmcnt(0) lgkmcnt(0)" ::: "memory");
    __builtin_amdgcn_sched_barrier(0);
    __builtin_amdgcn_s_barrier();
    if (k0 + 32 < F_DIM) STAGE_G2(c ^ 1, k0 + 32)
    const short* pA = &sA[c][0];
    const short* pB = &sB[c][0];
    bf16x8 af[4], bfr[4];
#pragma unroll
    for (int m = 0; m < 4; m++)
      af[m] = *(const bf16x8*)((const char*)pA + ((ra + m * 16) * 32 + kb) * 2);
#pragma unroll
    for (int n = 0; n < 4; n++)
      bfr[n] = *(const bf16x8*)((const char*)pB + ((rn + n * 16) * 32 + kb) * 2);
    __builtin_amdgcn_s_setprio(1);
#pragma unroll
    for (int m = 0; m < 4; m++)
#pragma unroll
      for (int n = 0; n < 4; n++)
        acc[m][n] = __builtin_amdgcn_mfma_f32_16x16x32_bf16(af[m], bfr[n], acc[m][n], 0, 0, 0);
    __builtin_amdgcn_s_setprio(0);
  }
  int rbase = wr * 64 + ((lane >> 4) << 2);
  int cbase = cb + wc * 64 + (lane & 15);
#pragma unroll
  for (int m = 0; m < 4; m++)
#pragma unroll
    for (int n = 0; n < 4; n++) {
      int d = cbase + n * 16;
      float bias = b2[e * D_DIM + d];
#pragma unroll
      for (int r = 0; r < 4; r++) {
        int p = rb + rbase + m * 16 + r;
        Y[(size_t)p * D_DIM + d] = f2bf(acc[m][n][r] + bias);
      }
    }
}

// ---------------- combine: out[t] = w1*Y[s1] + w2*Y[s2] ----------------
__global__ __launch_bounds__(256) void combine(const u16* __restrict__ Y,
                                               const int* __restrict__ meta,
                                               float* __restrict__ out) {
  int t = blockIdx.x;
  const int* ts = meta + MO_TSLOT / 4;
  const float* rw = (const float*)meta + MO_ROUTEW / 4;
  int s1 = ts[2 * t], s2 = ts[2 * t + 1];
  float w1 = rw[2 * t], w2 = rw[2 * t + 1];
  int d0 = threadIdx.x * 4;
  ushort4 a = *(const ushort4*)(Y + (size_t)s1 * D_DIM + d0);
  ushort4 b = *(const ushort4*)(Y + (size_t)s2 * D_DIM + d0);
  float4 v;
  v.x = w1 * bf2f(a.x) + w2 * bf2f(b.x);
  v.y = w1 * bf2f(a.y) + w2 * bf2f(b.y);
  v.z = w1 * bf2f(a.z) + w2 * bf2f(b.z);
  v.w = w1 * bf2f(a.w) + w2 * bf2f(b.w);
  *(float4*)(out + (size_t)t * D_DIM + d0) = v;
}

// ---------------- launch ----------------
extern "C" void kernel_launch(void* const* d_in, const int* in_sizes, int n_in,
                              void* d_out, int out_size, void* d_ws, size_t ws_size,
                              hipStream_t stream) {
  (void)in_sizes; (void)n_in; (void)out_size;
  const float* X    = (const float*)d_in[0];
  const float* TP   = (const float*)d_in[1];
  const float* Wg   = (const float*)d_in[2];
  const float* bg   = (const float*)d_in[3];
  const float* Wt   = (const float*)d_in[4];
  const float* bgt  = (const float*)d_in[5];
  const float* alp  = (const float*)d_in[6];
  const float* W1   = (const float*)d_in[7];
  const float* b1   = (const float*)d_in[8];
  const float* W2   = (const float*)d_in[9];
  const float* b2   = (const float*)d_in[10];
  float* out = (float*)d_out;
  char* ws = (char*)d_ws;
  u16* Xb = (u16*)(ws + A_XB);
  u16* WT = (u16*)(ws + A_WT);
  u16* H  = (u16*)(ws + A_H);
  u16* Y  = (u16*)(ws + A_Y);
  int* meta = (int*)(ws + A_META);

  int big = ws_size >= W2T_NEED;               // room for separate W2T?
  u16* W2T = big ? (u16*)(ws + A_W2T) : WT;

  prep<<<GBLK + 8192, 256, 0, stream>>>(X, TP, Wg, bg, Wt, bgt, alp, W1,
                                        Xb, WT, meta);
  plan<<<1, 64, 0, stream>>>(meta, out);
  fillk<<<T_TOK / 256, 256, 0, stream>>>(meta);
  // big mode: W2 transpose co-scheduled inside gemm1's grid (separate W2T
  // buffer; gemm2 is the only reader and launches after gemm1 drains).
  gemm1<<<4352 + (big ? 8192 : 0), 256, 0, stream>>>(Xb, WT, b1, H, W2, W2T, meta);
  if (!big) tcvt2k<<<8192, 256, 0, stream>>>(W2, WT);  // overwrite W1T after gemm1
  gemm2<<<1088, 256, 0, stream>>>(H, W2T, b2, Y, meta);
  combine<<<T_TOK, 256, 0, stream>>>(Y, meta, out);
}

// Round 11
// 533.637 us; speedup vs baseline: 1.4897x; 1.0364x over previous
//
#include <hip/hip_runtime.h>

// ---------------- problem constants ----------------
#define T_TOK 8192      // B*S tokens
#define D_DIM 1024
#define F_DIM 4096
#define E_EXP 8
#define DT_DIM 256
#define GBLK 256        // gating blocks (32 tokens each)

// ---------------- workspace layout (bytes) ----------------
#define A_XB   0u                    // bf16 X   [8192][1024]   16,777,216
#define A_WT   16777216u             // bf16 W1T (and W2T in small-ws mode)
#define A_H    83886080u             // bf16 h   [17408][4096] 142,606,336
#define A_Y    226492416u            // bf16 Y   [17408][1024]  35,651,584
#define A_META 262144000u
#define A_W2T  262428928u            // optional separate W2T (needs ws >= ~330MB)
#define W2T_NEED (262428928ull + 67108864ull)
// meta byte offsets
#define MO_FILL   0        // 8 ints (atomic fill cursors)
#define MO_PB     64       // 9 ints (expert segment bases)
#define MO_NT     128      // 1 int
#define MO_PARTP  256      // f32[256][8] per-block prob partials (8KB)
#define MO_PARTC  8448     // int[256][8] per-block count partials (8KB)
#define MO_TILEE  16640    // int[160]
#define MO_TILERB 17664    // int[160]
#define MO_ROUTEE 18688    // int[16384]
#define MO_ROUTEW 84224    // f32[16384]
#define MO_TSLOT  149760   // int[16384]
#define MO_PTOK   215296   // int[17408]
#define META_BYTES 284928

using bf16x8 = __attribute__((ext_vector_type(8))) short;
using f32x4  = __attribute__((ext_vector_type(4))) float;
typedef unsigned short u16;

__device__ __forceinline__ u16 f2bf(float f) {
  union { float f; unsigned u; } v; v.f = f;
  unsigned r = v.u + 0x7FFFu + ((v.u >> 16) & 1u);   // RNE
  return (u16)(r >> 16);
}
__device__ __forceinline__ float bf2f(u16 h) {
  union { unsigned u; float f; } v; v.u = ((unsigned)h) << 16; return v.f;
}
__device__ __forceinline__ void gload16(const void* gsrc, void* ldst) {
  __builtin_amdgcn_global_load_lds(
      (const __attribute__((address_space(1))) void*)gsrc,
      (__attribute__((address_space(3))) void*)ldst, 16, 0, 0);
}

// ---------------- 64x64 transpose+convert body (vectorized) ----------------
__device__ __forceinline__ void tcvt64_body(const float* __restrict__ src,
                                            u16* __restrict__ dst, int R, int C,
                                            int e, int rb, int cb, char* smem) {
  u16 (*tile)[65] = (u16(*)[65])smem;
  size_t off = (size_t)e * R * C;
  int t = threadIdx.x;
  int r = t >> 4, cq = (t & 15) << 2;
#pragma unroll
  for (int k = 0; k < 4; k++) {
    int rr = r + k * 16;
    float4 v = *(const float4*)(src + off + (size_t)(rb + rr) * C + cb + cq);
    tile[rr][cq] = f2bf(v.x);
    tile[rr][cq + 1] = f2bf(v.y);
    tile[rr][cq + 2] = f2bf(v.z);
    tile[rr][cq + 3] = f2bf(v.w);
  }
  __syncthreads();
  int r4 = (t & 15) << 2, c0 = t >> 4;
#pragma unroll
  for (int j = 0; j < 4; j++) {
    int c = c0 + j * 16;
    ushort4 o;
    o.x = tile[r4][c]; o.y = tile[r4 + 1][c];
    o.z = tile[r4 + 2][c]; o.w = tile[r4 + 3][c];
    *(ushort4*)(dst + off + (size_t)(cb + c) * R + rb + r4) = o;
  }
}

// ---------------- prep: fused gating + W1-tcvt ----------------
__global__ __launch_bounds__(256) void prep(
    const float* __restrict__ X, const float* __restrict__ TP,
    const float* __restrict__ Wg, const float* __restrict__ bg,
    const float* __restrict__ Wt, const float* __restrict__ bgt,
    const float* __restrict__ alphaP,
    const float* __restrict__ W1,
    u16* __restrict__ Xb, u16* __restrict__ W1T, int* meta) {
  __shared__ char smem[41216];
  int bid = blockIdx.x;
  if (bid >= GBLK) {
    int loc = bid - GBLK;   // W1 [e][1024][4096] -> W1T [e][4096][1024]
    int e = loc >> 10, t10 = loc & 1023;
    tcvt64_body(W1, W1T, D_DIM, F_DIM, e, (t10 & 15) << 6, (t10 >> 4) << 6, smem);
    return;
  }
  float* WgT = (float*)smem;                    // [e][d] 32KB
  float* WtT = (float*)(smem + 32768);          // 8KB
  float* wsP = (float*)(smem + 40960);
  int*   wsC = (int*)(smem + 41088);
  int tid = threadIdx.x;
  for (int i = tid; i < E_EXP * D_DIM; i += 256) { int d = i >> 3, e = i & 7; WgT[e * D_DIM + d] = Wg[i]; }
  for (int i = tid; i < E_EXP * DT_DIM; i += 256) { int d = i >> 3, e = i & 7; WtT[e * DT_DIM + d] = Wt[i]; }
  __syncthreads();
  int lane = tid & 63, wid = tid >> 6;
  int tb = bid * 32;
  int b = tb >> 11;  // S=2048
  float alpha = alphaP[0];

  float tac[8] = {};
#pragma unroll
  for (int i = 0; i < 4; i++) {
    int d = lane + i * 64;
    float x = TP[b * DT_DIM + d];
#pragma unroll
    for (int e = 0; e < 8; e++) tac[e] += x * WtT[e * DT_DIM + d];
  }
  for (int off = 32; off > 0; off >>= 1)
#pragma unroll
    for (int e = 0; e < 8; e++) tac[e] += __shfl_xor(tac[e], off);
  float tl[8];
#pragma unroll
  for (int e = 0; e < 8; e++) tl[e] = alpha * (tac[e] + bgt[e]);

  float psum[8] = {};
  int   cnt[8] = {};
  for (int i = 0; i < 8; i++) {
    int t = tb + wid * 8 + i;
    const float* xr = X + (size_t)t * D_DIM;
    float acc[8] = {};
    u16 xb[16];
#pragma unroll 4
    for (int j = 0; j < 16; j++) {
      int d = lane + j * 64;
      float x = xr[d];
      xb[j] = f2bf(x);
#pragma unroll
      for (int e = 0; e < 8; e++) acc[e] += x * WgT[e * D_DIM + d];
    }
#pragma unroll
    for (int j = 0; j < 16; j++) Xb[(size_t)t * D_DIM + lane + j * 64] = xb[j];
    for (int off = 32; off > 0; off >>= 1)
#pragma unroll
      for (int e = 0; e < 8; e++) acc[e] += __shfl_xor(acc[e], off);
    float gl[8];
#pragma unroll
    for (int e = 0; e < 8; e++) gl[e] = (1.f - alpha) * (acc[e] + bg[e]) + tl[e];
    int e1 = 0;
#pragma unroll
    for (int e = 1; e < 8; e++) if (gl[e] > gl[e1]) e1 = e;
    int es = (e1 == 0) ? 1 : 0;
#pragma unroll
    for (int e = 0; e < 8; e++) if (e != e1 && gl[e] > gl[es]) es = e;
    float mx = gl[0];
#pragma unroll
    for (int e = 1; e < 8; e++) mx = fmaxf(mx, gl[e]);
    float pe[8], se = 0.f;
#pragma unroll
    for (int e = 0; e < 8; e++) { pe[e] = __expf(gl[e] - mx); se += pe[e]; }
    float inv = 1.f / se;
    if (lane == 0) {
#pragma unroll
      for (int e = 0; e < 8; e++) psum[e] += pe[e] * inv;
      cnt[e1]++; cnt[es]++;
      float w1 = 1.f / (1.f + __expf(gl[es] - gl[e1]));
      meta[MO_ROUTEE / 4 + 2 * t] = e1;
      meta[MO_ROUTEE / 4 + 2 * t + 1] = es;
      ((float*)meta)[MO_ROUTEW / 4 + 2 * t] = w1;
      ((float*)meta)[MO_ROUTEW / 4 + 2 * t + 1] = 1.f - w1;
    }
  }
  if (lane == 0) {
#pragma unroll
    for (int e = 0; e < 8; e++) { wsP[wid * 8 + e] = psum[e]; wsC[wid * 8 + e] = cnt[e]; }
  }
  __syncthreads();
  if (tid < 8) {
    float p = wsP[tid] + wsP[8 + tid] + wsP[16 + tid] + wsP[24 + tid];
    int   c = wsC[tid] + wsC[8 + tid] + wsC[16 + tid] + wsC[24 + tid];
    ((float*)meta)[MO_PARTP / 4 + bid * 8 + tid] = p;
    meta[MO_PARTC / 4 + bid * 8 + tid] = c;
  }
}

// ---------------- standalone W2 tcvt (small-ws fallback, into WT) ----------
__global__ __launch_bounds__(256) void tcvt2k(const float* __restrict__ W2,
                                              u16* __restrict__ W2T) {
  __shared__ char smem[8448];
  int loc = blockIdx.x;
  int e = loc >> 10, t10 = loc & 1023;
  tcvt64_body(W2, W2T, F_DIM, D_DIM, e, (t10 >> 4) << 6, (t10 & 15) << 6, smem);
}

// ---------------- plan ----------------
__global__ void plan(int* meta, float* out) {
  __shared__ float sp[8];
  __shared__ int   sc[8];
  int tid = threadIdx.x;
  if (blockIdx.x != 0) return;
  if (tid < 8) {
    const float* pp = (const float*)meta + MO_PARTP / 4;
    const int*   pc = meta + MO_PARTC / 4;
    float p = 0.f; int c = 0;
    for (int b = 0; b < GBLK; b++) { p += pp[b * 8 + tid]; c += pc[b * 8 + tid]; }
    sp[tid] = p; sc[tid] = c;
    meta[MO_FILL / 4 + tid] = 0;
  }
  int* ptok = meta + MO_PTOK / 4;
  for (int i = tid; i < 17408; i += 64) ptok[i] = 0;
  __syncthreads();
  if (tid == 0) {
    int* pb = meta + MO_PB / 4;
    int* tileE = meta + MO_TILEE / 4;
    int* tileRB = meta + MO_TILERB / 4;
    int base = 0, nt = 0;
    float la = 0.f;
    for (int e = 0; e < 8; e++) {
      int n = sc[e];
      pb[e] = base;
      int ntl = (n + 127) >> 7;
      for (int i = 0; i < ntl; i++) { tileE[nt] = e; tileRB[nt] = base + (i << 7); nt++; }
      base += ntl << 7;
      la += (sp[e] * (1.f / 8192.f)) * ((float)n * (1.f / 8192.f));
    }
    pb[8] = base;
    meta[MO_NT / 4] = nt;
    out[T_TOK * D_DIM] = la;  // l_aux
  }
}

// ---------------- fill slot lists (wave-aggregated atomics) ----------------
__global__ __launch_bounds__(256) void fillk(int* meta) {
  int t = blockIdx.x * 256 + threadIdx.x;
  int lane = threadIdx.x & 63;
  int* pb = meta + MO_PB / 4;
  int* fl = meta + MO_FILL / 4;
  int* ptok = meta + MO_PTOK / 4;
  int* ts = meta + MO_TSLOT / 4;
  unsigned long long lmask = (1ull << lane) - 1;
#pragma unroll
  for (int k = 0; k < 2; k++) {
    int e = meta[MO_ROUTEE / 4 + 2 * t + k];
    int slot = 0;
    for (int ee = 0; ee < 8; ee++) {
      unsigned long long mask = __ballot(e == ee);
      if (e == ee) {
        int low = __ffsll((long long)mask) - 1;
        int pre = __popcll(mask & lmask);
        int base = 0;
        if (lane == low) base = atomicAdd(&fl[ee], __popcll(mask));
        base = __shfl(base, low);
        slot = pb[ee] + base + pre;
      }
    }
    ptok[slot] = t;
    ts[2 * t + k] = slot;
  }
}

// =====================================================================
// GEMM core: 128x128 tile, BK=32, 256 thr, 4 waves x 64x64, T2 XOR
// swizzle. NEW: 3-buffer LDS (48KB), distance-2 prefetch, counted
// vmcnt(4) (T4): stage(k+2) issued at iter k; its wait is two compute
// phases later -> covers L2 (~200cy) and most HBM latency without
// relying on inter-block TLP (stuck at ~2 blocks/CU, r2-r10 history).
// Wait drains exactly stage(k): outstanding = stage(k)+stage(k+1)=8,
// vmcnt(4) leaves stage(k+1) in flight. Last iter: vmcnt(0).
// Race: per-wave lgkmcnt(0) before barrier(k) retires reads of the
// buffer stage(k+2) overwrites (read at iter k-1).
// =====================================================================

#define BUFA(i) ((char*)smem + (i) * 16384)
#define BUFB(i) ((char*)smem + (i) * 16384 + 8192)

// ---------------- GEMM1 (+ co-scheduled W2 tcvt in big-ws mode) ----------
__global__ __launch_bounds__(256) void gemm1(
    const u16* __restrict__ Xb, const u16* __restrict__ W1T,
    const float* __restrict__ b1, u16* __restrict__ H,
    const float* __restrict__ W2, u16* __restrict__ W2T,
    const int* __restrict__ meta) {
  __shared__ char smem[49152];
  if (blockIdx.x >= 4352) {     // W2 [e][4096][1024] -> W2T [e][1024][4096]
    int loc = blockIdx.x - 4352;
    int e = loc >> 10, t10 = loc & 1023;
    tcvt64_body(W2, W2T, F_DIM, D_DIM, e, (t10 >> 4) << 6, (t10 & 15) << 6, smem);
    return;
  }
  int xcd = blockIdx.x & 7, loc = blockIdx.x >> 3;   // 4352 = 8*544
  int bt = loc >> 2;
  int cb = (xcd * 4 + (loc & 3)) * 128;
  int nt = meta[MO_NT / 4];
  if (bt >= nt) return;
  int e = meta[MO_TILEE / 4 + bt];
  int rb = meta[MO_TILERB / 4 + bt];
  const int* ptok = meta + MO_PTOK / 4;

  int tid = threadIdx.x, lane = tid & 63, wid = tid >> 6;
  int wr = wid >> 1, wc = wid & 1;
  int r0 = tid >> 2;
  int c0 = (((tid & 3) ^ ((r0 >> 1) & 3)) << 3);   // swizzled source granule
  int tok0 = ptok[rb + r0];
  int tok1 = ptok[rb + r0 + 64];
  const u16* gA0 = Xb + (size_t)tok0 * D_DIM + c0;
  const u16* gA1 = Xb + (size_t)tok1 * D_DIM + c0;
  const u16* gB0 = W1T + ((size_t)e * F_DIM + cb + r0) * D_DIM + c0;
  const u16* gB1 = gB0 + (size_t)64 * D_DIM;

#define STAGE_G1(buf, k0)                                  \
  {                                                        \
    gload16(gA0 + (k0), BUFA(buf) + wid * 1024);           \
    gload16(gA1 + (k0), BUFA(buf) + 4096 + wid * 1024);    \
    gload16(gB0 + (k0), BUFB(buf) + wid * 1024);           \
    gload16(gB1 + (k0), BUFB(buf) + 4096 + wid * 1024);    \
  }

  f32x4 acc[4][4] = {};
  int kb = (((lane >> 4) ^ (((lane & 15) >> 1) & 3)) << 3);  // swizzled read granule
  int ra = wr * 64 + (lane & 15);
  int rn = wc * 64 + (lane & 15);
  STAGE_G1(0, 0)
  STAGE_G1(1, 32)
  int cur = 0;
  for (int kt = 0; kt < 32; kt++) {
    if (kt + 1 < 32)
      asm volatile("s_waitcnt vmcnt(4) lgkmcnt(0)" ::: "memory");
    else
      asm volatile("s_waitcnt vmcnt(0) lgkmcnt(0)" ::: "memory");
    __builtin_amdgcn_sched_barrier(0);
    __builtin_amdgcn_s_barrier();
    int nxt = cur + 2; if (nxt >= 3) nxt -= 3;
    if (kt + 2 < 32) STAGE_G1(nxt, (kt + 2) * 32)
    const short* pA = (const short*)BUFA(cur);
    const short* pB = (const short*)BUFB(cur);
    bf16x8 af[4], bfr[4];
#pragma unroll
    for (int m = 0; m < 4; m++)
      af[m] = *(const bf16x8*)((const char*)pA + ((ra + m * 16) * 32 + kb) * 2);
#pragma unroll
    for (int n = 0; n < 4; n++)
      bfr[n] = *(const bf16x8*)((const char*)pB + ((rn + n * 16) * 32 + kb) * 2);
    __builtin_amdgcn_s_setprio(1);
#pragma unroll
    for (int m = 0; m < 4; m++)
#pragma unroll
      for (int n = 0; n < 4; n++)
        acc[m][n] = __builtin_amdgcn_mfma_f32_16x16x32_bf16(af[m], bfr[n], acc[m][n], 0, 0, 0);
    __builtin_amdgcn_s_setprio(0);
    cur = cur + 1 == 3 ? 0 : cur + 1;
  }
  int rbase = wr * 64 + ((lane >> 4) << 2);
  int cbase = cb + wc * 64 + (lane & 15);
#pragma unroll
  for (int m = 0; m < 4; m++)
#pragma unroll
    for (int n = 0; n < 4; n++) {
      int f = cbase + n * 16;
      float bias = b1[e * F_DIM + f];
#pragma unroll
      for (int r = 0; r < 4; r++) {
        int p = rb + rbase + m * 16 + r;
        float v = acc[m][n][r] + bias;
        float s = v * (1.0f / (1.0f + __expf(-v)));
        H[(size_t)p * F_DIM + f] = f2bf(s);
      }
    }
}

// ---------------- GEMM2: Y = h @ W2[e] + b2[e] ----------------
__global__ __launch_bounds__(256) void gemm2(
    const u16* __restrict__ H, const u16* __restrict__ W2T,
    const float* __restrict__ b2, u16* __restrict__ Y, const int* __restrict__ meta) {
  __shared__ char smem[49152];
  int id = blockIdx.x;
  int wg = (id & 7) * 136 + (id >> 3);   // bijective, 1088 = 8*136
  int bt = wg >> 3;
  int cb = (wg & 7) * 128;
  int nt = meta[MO_NT / 4];
  if (bt >= nt) return;
  int e = meta[MO_TILEE / 4 + bt];
  int rb = meta[MO_TILERB / 4 + bt];
  int tid = threadIdx.x, lane = tid & 63, wid = tid >> 6;
  int wr = wid >> 1, wc = wid & 1;
  int r0 = tid >> 2;
  int c0 = (((tid & 3) ^ ((r0 >> 1) & 3)) << 3);   // swizzled source granule
  const u16* gA0 = H + (size_t)(rb + r0) * F_DIM + c0;
  const u16* gA1 = gA0 + (size_t)64 * F_DIM;
  const u16* gB0 = W2T + ((size_t)e * D_DIM + cb + r0) * F_DIM + c0;
  const u16* gB1 = gB0 + (size_t)64 * F_DIM;

#define STAGE_G2(buf, k0)                                  \
  {                                                        \
    gload16(gA0 + (k0), BUFA(buf) + wid * 1024);           \
    gload16(gA1 + (k0), BUFA(buf) + 4096 + wid * 1024);    \
    gload16(gB0 + (k0), BUFB(buf) + wid * 1024);           \
    gload16(gB1 + (k0), BUFB(buf) + 4096 + wid * 1024);    \
  }

  f32x4 acc[4][4] = {};
  int kb = (((lane >> 4) ^ (((lane & 15) >> 1) & 3)) << 3);  // swizzled read granule
  int ra = wr * 64 + (lane & 15);
  int rn = wc * 64 + (lane & 15);
  STAGE_G2(0, 0)
  STAGE_G2(1, 32)
  int cur = 0;
  for (int kt = 0; kt < 128; kt++) {
    if (kt + 1 < 128)
      asm volatile("s_waitcnt vmcnt(4) lgkmcnt(0)" ::: "memory");
    else
      asm volatile("s_waitcnt vmcnt(0) lgkmcnt(0)" ::: "memory");
    __builtin_amdgcn_sched_barrier(0);
    __builtin_amdgcn_s_barrier();
    int nxt = cur + 2; if (nxt >= 3) nxt -= 3;
    if (kt + 2 < 128) STAGE_G2(nxt, (kt + 2) * 32)
    const short* pA = (const short*)BUFA(cur);
    const short* pB = (const short*)BUFB(cur);
    bf16x8 af[4], bfr[4];
#pragma unroll
    for (int m = 0; m < 4; m++)
      af[m] = *(const bf16x8*)((const char*)pA + ((ra + m * 16) * 32 + kb) * 2);
#pragma unroll
    for (int n = 0; n < 4; n++)
      bfr[n] = *(const bf16x8*)((const char*)pB + ((rn + n * 16) * 32 + kb) * 2);
    __builtin_amdgcn_s_setprio(1);
#pragma unroll
    for (int m = 0; m < 4; m++)
#pragma unroll
      for (int n = 0; n < 4; n++)
        acc[m][n] = __builtin_amdgcn_mfma_f32_16x16x32_bf16(af[m], bfr[n], acc[m][n], 0, 0, 0);
    __builtin_amdgcn_s_setprio(0);
    cur = cur + 1 == 3 ? 0 : cur + 1;
  }
  int rbase = wr * 64 + ((lane >> 4) << 2);
  int cbase = cb + wc * 64 + (lane & 15);
#pragma unroll
  for (int m = 0; m < 4; m++)
#pragma unroll
    for (int n = 0; n < 4; n++) {
      int d = cbase + n * 16;
      float bias = b2[e * D_DIM + d];
#pragma unroll
      for (int r = 0; r < 4; r++) {
        int p = rb + rbase + m * 16 + r;
        Y[(size_t)p * D_DIM + d] = f2bf(acc[m][n][r] + bias);
      }
    }
}

// ---------------- combine: out[t] = w1*Y[s1] + w2*Y[s2] ----------------
__global__ __launch_bounds__(256) void combine(const u16* __restrict__ Y,
                                               const int* __restrict__ meta,
                                               float* __restrict__ out) {
  int t = blockIdx.x;
  const int* ts = meta + MO_TSLOT / 4;
  const float* rw = (const float*)meta + MO_ROUTEW / 4;
  int s1 = ts[2 * t], s2 = ts[2 * t + 1];
  float w1 = rw[2 * t], w2 = rw[2 * t + 1];
  int d0 = threadIdx.x * 4;
  ushort4 a = *(const ushort4*)(Y + (size_t)s1 * D_DIM + d0);
  ushort4 b = *(const ushort4*)(Y + (size_t)s2 * D_DIM + d0);
  float4 v;
  v.x = w1 * bf2f(a.x) + w2 * bf2f(b.x);
  v.y = w1 * bf2f(a.y) + w2 * bf2f(b.y);
  v.z = w1 * bf2f(a.z) + w2 * bf2f(b.z);
  v.w = w1 * bf2f(a.w) + w2 * bf2f(b.w);
  *(float4*)(out + (size_t)t * D_DIM + d0) = v;
}

// ---------------- launch ----------------
extern "C" void kernel_launch(void* const* d_in, const int* in_sizes, int n_in,
                              void* d_out, int out_size, void* d_ws, size_t ws_size,
                              hipStream_t stream) {
  (void)in_sizes; (void)n_in; (void)out_size;
  const float* X    = (const float*)d_in[0];
  const float* TP   = (const float*)d_in[1];
  const float* Wg   = (const float*)d_in[2];
  const float* bg   = (const float*)d_in[3];
  const float* Wt   = (const float*)d_in[4];
  const float* bgt  = (const float*)d_in[5];
  const float* alp  = (const float*)d_in[6];
  const float* W1   = (const float*)d_in[7];
  const float* b1   = (const float*)d_in[8];
  const float* W2   = (const float*)d_in[9];
  const float* b2   = (const float*)d_in[10];
  float* out = (float*)d_out;
  char* ws = (char*)d_ws;
  u16* Xb = (u16*)(ws + A_XB);
  u16* WT = (u16*)(ws + A_WT);
  u16* H  = (u16*)(ws + A_H);
  u16* Y  = (u16*)(ws + A_Y);
  int* meta = (int*)(ws + A_META);

  int big = ws_size >= W2T_NEED;               // room for separate W2T?
  u16* W2T = big ? (u16*)(ws + A_W2T) : WT;

  prep<<<GBLK + 8192, 256, 0, stream>>>(X, TP, Wg, bg, Wt, bgt, alp, W1,
                                        Xb, WT, meta);
  plan<<<1, 64, 0, stream>>>(meta, out);
  fillk<<<T_TOK / 256, 256, 0, stream>>>(meta);
  gemm1<<<4352 + (big ? 8192 : 0), 256, 0, stream>>>(Xb, WT, b1, H, W2, W2T, meta);
  if (!big) tcvt2k<<<8192, 256, 0, stream>>>(W2, WT);
  gemm2<<<1088, 256, 0, stream>>>(H, W2T, b2, Y, meta);
  combine<<<T_TOK, 256, 0, stream>>>(Y, meta, out);
}